// Round 1
// baseline (155.527 us; speedup 1.0000x reference)
//
#include <hip/hip_runtime.h>
#include <hip/hip_bf16.h>

typedef unsigned short u16;
typedef unsigned int u32;
typedef __attribute__((ext_vector_type(4))) float f32x4;
typedef __attribute__((ext_vector_type(4))) u32 u32x4;
typedef __attribute__((ext_vector_type(8))) __bf16 bf16x8;

#define SQ 3072
#define NH 4
#define DH 32

static __device__ __forceinline__ u16 f2bf(float f) {
  return __builtin_bit_cast(u16, (__bf16)f);
}
static __device__ __forceinline__ u32 pk2(float a, float b) {
  return (u32)f2bf(a) | ((u32)f2bf(b) << 16);
}
static __device__ __forceinline__ bf16x8 ld8(const u16* p) {
  return __builtin_bit_cast(bf16x8, *reinterpret_cast<const u32x4*>(p));
}
static __device__ __forceinline__ f32x4 mfma16(bf16x8 a, bf16x8 b, f32x4 c) {
  return __builtin_amdgcn_mfma_f32_16x16x32_bf16(a, b, c, 0, 0, 0);
}
static __device__ __forceinline__ float sigm(float x) { return 1.0f / (1.0f + __expf(-x)); }
static __device__ __forceinline__ float red8(float v) {
  v += __shfl_xor(v, 1); v += __shfl_xor(v, 2); v += __shfl_xor(v, 4);
  return v;
}

// A: 32x128 bf16 in LDS (row stride 136). B: WT[cout][k] bf16 (128x128, row stride 128).
// Computes D tiles: rows mt*16 + lg*4 + r (mt=0,1), cols (wave*2+j)*16 + lr (j=0,1).
static __device__ __forceinline__ void gemm32x128(
    const u16* a, const u16* wt, int lr, int lg, int wave, f32x4 d[2][2]) {
  f32x4 z = {0.f, 0.f, 0.f, 0.f};
  d[0][0] = z; d[0][1] = z; d[1][0] = z; d[1][1] = z;
#pragma unroll
  for (int kc = 0; kc < 4; ++kc) {
    int ko = kc * 32 + lg * 8;
    bf16x8 a0 = ld8(a + lr * 136 + ko);
    bf16x8 a1 = ld8(a + (16 + lr) * 136 + ko);
    bf16x8 b0 = ld8(wt + ((wave * 2 + 0) * 16 + lr) * 128 + ko);
    bf16x8 b1 = ld8(wt + ((wave * 2 + 1) * 16 + lr) * 128 + ko);
    d[0][0] = mfma16(a0, b0, d[0][0]);
    d[1][0] = mfma16(a1, b0, d[1][0]);
    d[0][1] = mfma16(a0, b1, d[0][1]);
    d[1][1] = mfma16(a1, b1, d[1][1]);
  }
}

struct PrepSrc { const float* p[10]; };

// Transpose + bf16-cast ten 128x128 weight matrices: dst[m][cout][k] = W_m[k][cout]
__global__ __launch_bounds__(256) void prep(PrepSrc s, u16* __restrict__ dst) {
  int bid = blockIdx.x;
  int mm = bid >> 6;
  int idx = ((bid & 63) << 8) + threadIdx.x;  // = cout*128 + k
  int co = idx >> 7, k = idx & 127;
  dst[mm * 16384 + idx] = f2bf(s.p[mm][k * 128 + co]);
}

// q-side: LN(x), LN(cond)*gamma -> cn; scale/bias GEMMs -> xa; Q/gate/zc GEMMs.
__global__ __launch_bounds__(256) void rowblock_q(
    const float* __restrict__ x, const float* __restrict__ cond,
    const float* __restrict__ gamma, const float* __restrict__ bs,
    const float* __restrict__ bq, const float* __restrict__ bzc,
    const u16* __restrict__ WT,
    u16* __restrict__ qbf, float* __restrict__ gate, float* __restrict__ zc) {
  __shared__ float xnf[32 * 132];
  __shared__ u16 a_cn[32 * 136];
  __shared__ u16 a_raw[32 * 136];
  __shared__ u16 a_xa[32 * 136];
  const int tid = threadIdx.x;
  const int rl = tid >> 3, sub = tid & 7, c0 = sub * 16;
  const size_t grow = (size_t)blockIdx.x * 32 + rl;

  {  // LN(x) -> xnf (f32)
    float xs[16];
    const float4* xr = reinterpret_cast<const float4*>(x + grow * 128 + c0);
#pragma unroll
    for (int i = 0; i < 4; ++i) { float4 t = xr[i]; xs[4*i]=t.x; xs[4*i+1]=t.y; xs[4*i+2]=t.z; xs[4*i+3]=t.w; }
    float s = 0.f;
#pragma unroll
    for (int i = 0; i < 16; ++i) s += xs[i];
    float mean = red8(s) * (1.f / 128.f);
    float vs = 0.f;
#pragma unroll
    for (int i = 0; i < 16; ++i) { float dd = xs[i] - mean; vs += dd * dd; }
    float rstd = rsqrtf(red8(vs) * (1.f / 128.f) + 1e-5f);
    float4* xw = reinterpret_cast<float4*>(&xnf[rl * 132 + c0]);
#pragma unroll
    for (int i = 0; i < 4; ++i) {
      float4 t;
      t.x = (xs[4*i+0] - mean) * rstd; t.y = (xs[4*i+1] - mean) * rstd;
      t.z = (xs[4*i+2] - mean) * rstd; t.w = (xs[4*i+3] - mean) * rstd;
      xw[i] = t;
    }
  }
  {  // LN(cond)*gamma -> a_cn (bf16); raw cond -> a_raw (bf16)
    float cs[16], gs[16];
    const float4* cr = reinterpret_cast<const float4*>(cond + grow * 128 + c0);
    const float4* gr = reinterpret_cast<const float4*>(gamma + c0);
#pragma unroll
    for (int i = 0; i < 4; ++i) { float4 t = cr[i]; cs[4*i]=t.x; cs[4*i+1]=t.y; cs[4*i+2]=t.z; cs[4*i+3]=t.w; }
#pragma unroll
    for (int i = 0; i < 4; ++i) { float4 t = gr[i]; gs[4*i]=t.x; gs[4*i+1]=t.y; gs[4*i+2]=t.z; gs[4*i+3]=t.w; }
    float s = 0.f;
#pragma unroll
    for (int i = 0; i < 16; ++i) s += cs[i];
    float mean = red8(s) * (1.f / 128.f);
    float vs = 0.f;
#pragma unroll
    for (int i = 0; i < 16; ++i) { float dd = cs[i] - mean; vs += dd * dd; }
    float rstd = rsqrtf(red8(vs) * (1.f / 128.f) + 1e-5f);
    float cn[16];
#pragma unroll
    for (int i = 0; i < 16; ++i) cn[i] = (cs[i] - mean) * rstd * gs[i];
    u32x4* cw = reinterpret_cast<u32x4*>(&a_cn[rl * 136 + c0]);
    u32x4 w0 = {pk2(cn[0],cn[1]), pk2(cn[2],cn[3]), pk2(cn[4],cn[5]), pk2(cn[6],cn[7])};
    u32x4 w1 = {pk2(cn[8],cn[9]), pk2(cn[10],cn[11]), pk2(cn[12],cn[13]), pk2(cn[14],cn[15])};
    cw[0] = w0; cw[1] = w1;
    u32x4* rw = reinterpret_cast<u32x4*>(&a_raw[rl * 136 + c0]);
    u32x4 r0 = {pk2(cs[0],cs[1]), pk2(cs[2],cs[3]), pk2(cs[4],cs[5]), pk2(cs[6],cs[7])};
    u32x4 r1 = {pk2(cs[8],cs[9]), pk2(cs[10],cs[11]), pk2(cs[12],cs[13]), pk2(cs[14],cs[15])};
    rw[0] = r0; rw[1] = r1;
  }
  __syncthreads();
  const int lane = tid & 63, wave = tid >> 6, lr = lane & 15, lg = lane >> 4;
  f32x4 dS[2][2], dB[2][2];
  gemm32x128(a_cn, WT + 0 * 16384, lr, lg, wave, dS);
  gemm32x128(a_cn, WT + 1 * 16384, lr, lg, wave, dB);
#pragma unroll
  for (int mt = 0; mt < 2; ++mt)
#pragma unroll
    for (int j = 0; j < 2; ++j)
#pragma unroll
      for (int r = 0; r < 4; ++r) {
        int col = (wave * 2 + j) * 16 + lr;
        int rowl = mt * 16 + lg * 4 + r;
        float sc = dS[mt][j][r] + bs[col];
        float xa = sigm(sc) * xnf[rowl * 132 + col] + dB[mt][j][r];
        a_xa[rowl * 136 + col] = f2bf(xa);
      }
  __syncthreads();
  f32x4 dQ[2][2], dG[2][2], dZ[2][2];
  gemm32x128(a_xa, WT + 2 * 16384, lr, lg, wave, dQ);
  gemm32x128(a_xa, WT + 3 * 16384, lr, lg, wave, dG);
  gemm32x128(a_raw, WT + 4 * 16384, lr, lg, wave, dZ);
#pragma unroll
  for (int mt = 0; mt < 2; ++mt)
#pragma unroll
    for (int j = 0; j < 2; ++j)
#pragma unroll
      for (int r = 0; r < 4; ++r) {
        int col = (wave * 2 + j) * 16 + lr;
        int rowl = mt * 16 + lg * 4 + r;
        size_t gr = (size_t)blockIdx.x * 32 + rowl;
        int b = (int)(gr >= SQ);
        int pos = (int)gr - b * SQ;
        float qv = (dQ[mt][j][r] + bq[col]) * 0.17677669529663687f;  // Dh^-0.5
        qbf[(((size_t)b * NH + (col >> 5)) * SQ + pos) * DH + (col & 31)] = f2bf(qv);
        gate[gr * 128 + col] = sigm(dG[mt][j][r]);
        zc[gr * 128 + col] = sigm(dZ[mt][j][r] + bzc[col]);
      }
}

// k-side: produces kbf [b,h,k,d] and vT [b,h,d,k] (both bf16).
__global__ __launch_bounds__(256) void rowblock_k(
    const float* __restrict__ x, const float* __restrict__ cond,
    const float* __restrict__ gamma, const float* __restrict__ bs,
    const u16* __restrict__ WT,
    u16* __restrict__ kbf, u16* __restrict__ vT) {
  __shared__ float xnf[32 * 132];
  __shared__ u16 a_cn[32 * 136];
  __shared__ u16 a_xa[32 * 136];
  const int tid = threadIdx.x;
  const int rl = tid >> 3, sub = tid & 7, c0 = sub * 16;
  const size_t grow = (size_t)blockIdx.x * 32 + rl;
  {
    float xs[16];
    const float4* xr = reinterpret_cast<const float4*>(x + grow * 128 + c0);
#pragma unroll
    for (int i = 0; i < 4; ++i) { float4 t = xr[i]; xs[4*i]=t.x; xs[4*i+1]=t.y; xs[4*i+2]=t.z; xs[4*i+3]=t.w; }
    float s = 0.f;
#pragma unroll
    for (int i = 0; i < 16; ++i) s += xs[i];
    float mean = red8(s) * (1.f / 128.f);
    float vs = 0.f;
#pragma unroll
    for (int i = 0; i < 16; ++i) { float dd = xs[i] - mean; vs += dd * dd; }
    float rstd = rsqrtf(red8(vs) * (1.f / 128.f) + 1e-5f);
    float4* xw = reinterpret_cast<float4*>(&xnf[rl * 132 + c0]);
#pragma unroll
    for (int i = 0; i < 4; ++i) {
      float4 t;
      t.x = (xs[4*i+0] - mean) * rstd; t.y = (xs[4*i+1] - mean) * rstd;
      t.z = (xs[4*i+2] - mean) * rstd; t.w = (xs[4*i+3] - mean) * rstd;
      xw[i] = t;
    }
  }
  {
    float cs[16], gs[16];
    const float4* cr = reinterpret_cast<const float4*>(cond + grow * 128 + c0);
    const float4* gr = reinterpret_cast<const float4*>(gamma + c0);
#pragma unroll
    for (int i = 0; i < 4; ++i) { float4 t = cr[i]; cs[4*i]=t.x; cs[4*i+1]=t.y; cs[4*i+2]=t.z; cs[4*i+3]=t.w; }
#pragma unroll
    for (int i = 0; i < 4; ++i) { float4 t = gr[i]; gs[4*i]=t.x; gs[4*i+1]=t.y; gs[4*i+2]=t.z; gs[4*i+3]=t.w; }
    float s = 0.f;
#pragma unroll
    for (int i = 0; i < 16; ++i) s += cs[i];
    float mean = red8(s) * (1.f / 128.f);
    float vs = 0.f;
#pragma unroll
    for (int i = 0; i < 16; ++i) { float dd = cs[i] - mean; vs += dd * dd; }
    float rstd = rsqrtf(red8(vs) * (1.f / 128.f) + 1e-5f);
    float cn[16];
#pragma unroll
    for (int i = 0; i < 16; ++i) cn[i] = (cs[i] - mean) * rstd * gs[i];
    u32x4* cw = reinterpret_cast<u32x4*>(&a_cn[rl * 136 + c0]);
    u32x4 w0 = {pk2(cn[0],cn[1]), pk2(cn[2],cn[3]), pk2(cn[4],cn[5]), pk2(cn[6],cn[7])};
    u32x4 w1 = {pk2(cn[8],cn[9]), pk2(cn[10],cn[11]), pk2(cn[12],cn[13]), pk2(cn[14],cn[15])};
    cw[0] = w0; cw[1] = w1;
  }
  __syncthreads();
  const int lane = tid & 63, wave = tid >> 6, lr = lane & 15, lg = lane >> 4;
  f32x4 dS[2][2], dB[2][2];
  gemm32x128(a_cn, WT + 5 * 16384, lr, lg, wave, dS);
  gemm32x128(a_cn, WT + 6 * 16384, lr, lg, wave, dB);
#pragma unroll
  for (int mt = 0; mt < 2; ++mt)
#pragma unroll
    for (int j = 0; j < 2; ++j)
#pragma unroll
      for (int r = 0; r < 4; ++r) {
        int col = (wave * 2 + j) * 16 + lr;
        int rowl = mt * 16 + lg * 4 + r;
        float sc = dS[mt][j][r] + bs[col];
        float xa = sigm(sc) * xnf[rowl * 132 + col] + dB[mt][j][r];
        a_xa[rowl * 136 + col] = f2bf(xa);
      }
  __syncthreads();
  f32x4 dK[2][2], dV[2][2];
  gemm32x128(a_xa, WT + 7 * 16384, lr, lg, wave, dK);
  gemm32x128(a_xa, WT + 8 * 16384, lr, lg, wave, dV);
#pragma unroll
  for (int mt = 0; mt < 2; ++mt)
#pragma unroll
    for (int j = 0; j < 2; ++j)
#pragma unroll
      for (int r = 0; r < 4; ++r) {
        int col = (wave * 2 + j) * 16 + lr;
        int rowl = mt * 16 + lg * 4 + r;
        size_t gr = (size_t)blockIdx.x * 32 + rowl;
        int b = (int)(gr >= SQ);
        int pos = (int)gr - b * SQ;
        int h = col >> 5, dd = col & 31;
        kbf[(((size_t)b * NH + h) * SQ + pos) * DH + dd] = f2bf(dK[mt][j][r]);
        vT[(((size_t)b * NH + h) * DH + dd) * SQ + pos] = f2bf(dV[mt][j][r]);
      }
}

// Flash attention: one wave = 16 q rows, 64-key steps, online softmax.
__global__ __launch_bounds__(128) void attn(
    const u16* __restrict__ qbf, const u16* __restrict__ kbf, const u16* __restrict__ vT,
    const float* __restrict__ pair, const int* __restrict__ mask_q,
    const int* __restrict__ mask_k, const float* __restrict__ gate,
    u16* __restrict__ wa) {
  __shared__ u16 plds[2][16 * 72];
  const int tid = threadIdx.x, lane = tid & 63, wave = tid >> 6, lr = lane & 15, lg = lane >> 4;
  const int bh = blockIdx.y, b = bh >> 2, h = bh & 3;
  const int q0 = blockIdx.x * 32 + wave * 16;
  const bf16x8 aq = ld8(qbf + ((size_t)bh * SQ + q0 + lr) * DH + lg * 8);
  float mqm1[4];
#pragma unroll
  for (int r = 0; r < 4; ++r)
    mqm1[r] = 1e9f * ((float)mask_q[b * SQ + q0 + lg * 4 + r] - 1.f);
  float m[4], l[4];
#pragma unroll
  for (int r = 0; r < 4; ++r) { m[r] = -1e30f; l[r] = 0.f; }
  const f32x4 zero = {0.f, 0.f, 0.f, 0.f};
  f32x4 o[2]; o[0] = zero; o[1] = zero;
  const float* prow = pair + ((size_t)bh * SQ + q0 + lg * 4) * SQ;
  u16* pw = plds[wave];
  for (int kb = 0; kb < SQ; kb += 64) {
    f32x4 s[4];
#pragma unroll
    for (int kt = 0; kt < 4; ++kt)
      s[kt] = mfma16(aq, ld8(kbf + ((size_t)bh * SQ + kb + kt * 16 + lr) * DH + lg * 8), zero);
    float mk1[4];
#pragma unroll
    for (int kt = 0; kt < 4; ++kt)
      mk1[kt] = (float)mask_k[b * SQ + kb + kt * 16 + lr] - 1.f;
#pragma unroll
    for (int kt = 0; kt < 4; ++kt) {
      const float* pc = prow + kb + kt * 16 + lr;
#pragma unroll
      for (int r = 0; r < 4; ++r) {
        float pv = __builtin_nontemporal_load(pc + (size_t)r * SQ);
        s[kt][r] += fmaf(mqm1[r], mk1[kt], pv);  // exact-1e9 masking preserved
      }
    }
    float alpha[4];
#pragma unroll
    for (int r = 0; r < 4; ++r) {
      float mx = fmaxf(fmaxf(s[0][r], s[1][r]), fmaxf(s[2][r], s[3][r]));
      mx = fmaxf(mx, __shfl_xor(mx, 1));
      mx = fmaxf(mx, __shfl_xor(mx, 2));
      mx = fmaxf(mx, __shfl_xor(mx, 4));
      mx = fmaxf(mx, __shfl_xor(mx, 8));
      float mn = fmaxf(m[r], mx);
      alpha[r] = __expf(m[r] - mn);
      m[r] = mn;
    }
#pragma unroll
    for (int r = 0; r < 4; ++r) {
      float acc = 0.f;
#pragma unroll
      for (int kt = 0; kt < 4; ++kt) {
        float p = __expf(s[kt][r] - m[r]);
        s[kt][r] = p;
        acc += p;
      }
      acc += __shfl_xor(acc, 1); acc += __shfl_xor(acc, 2);
      acc += __shfl_xor(acc, 4); acc += __shfl_xor(acc, 8);
      l[r] = l[r] * alpha[r] + acc;
      o[0][r] *= alpha[r];
      o[1][r] *= alpha[r];
    }
#pragma unroll
    for (int kt = 0; kt < 4; ++kt)
#pragma unroll
      for (int r = 0; r < 4; ++r)
        pw[(lg * 4 + r) * 72 + kt * 16 + lr] = f2bf(s[kt][r]);
#pragma unroll
    for (int kc = 0; kc < 2; ++kc) {
      bf16x8 pa = ld8(pw + lr * 72 + kc * 32 + lg * 8);
#pragma unroll
      for (int hf = 0; hf < 2; ++hf) {
        bf16x8 bv = ld8(vT + ((size_t)bh * DH + hf * 16 + lr) * SQ + kb + kc * 32 + lg * 8);
        o[hf] = mfma16(pa, bv, o[hf]);
      }
    }
  }
#pragma unroll
  for (int hf = 0; hf < 2; ++hf)
#pragma unroll
    for (int r = 0; r < 4; ++r) {
      int q = q0 + lg * 4 + r;
      int c = h * 32 + hf * 16 + lr;
      size_t gi = ((size_t)b * SQ + q) * 128 + c;
      float v = o[hf][r] / l[r];
      wa[gi] = f2bf(v * gate[gi]);
    }
}

// out = (wa @ Wt2) * zc
__global__ __launch_bounds__(256) void finalk(
    const u16* __restrict__ wa, const u16* __restrict__ WTt2,
    const float* __restrict__ zc, float* __restrict__ out) {
  __shared__ u16 awa[32 * 136];
  const int tid = threadIdx.x, rl = tid >> 3, sub = tid & 7, c0 = sub * 16;
  const size_t grow = (size_t)blockIdx.x * 32 + rl;
  const u32x4* srcp = reinterpret_cast<const u32x4*>(wa + grow * 128 + c0);
  u32x4* dstp = reinterpret_cast<u32x4*>(&awa[rl * 136 + c0]);
  dstp[0] = srcp[0];
  dstp[1] = srcp[1];
  __syncthreads();
  const int lane = tid & 63, wave = tid >> 6, lr = lane & 15, lg = lane >> 4;
  f32x4 d[2][2];
  gemm32x128(awa, WTt2, lr, lg, wave, d);
#pragma unroll
  for (int mt = 0; mt < 2; ++mt)
#pragma unroll
    for (int j = 0; j < 2; ++j)
#pragma unroll
      for (int r = 0; r < 4; ++r) {
        int col = (wave * 2 + j) * 16 + lr;
        size_t gr = (size_t)blockIdx.x * 32 + mt * 16 + lg * 4 + r;
        out[gr * 128 + col] = d[mt][j][r] * zc[gr * 128 + col];
      }
}

extern "C" void kernel_launch(void* const* d_in, const int* in_sizes, int n_in,
                              void* d_out, int out_size, void* d_ws, size_t ws_size,
                              hipStream_t stream) {
  const float* x_q   = (const float*)d_in[0];
  const float* x_k   = (const float*)d_in[1];
  const int* mask_q  = (const int*)d_in[2];
  const int* mask_k  = (const int*)d_in[3];
  const float* pair  = (const float*)d_in[4];
  const float* scq   = (const float*)d_in[5];
  const float* sck   = (const float*)d_in[6];
  const float* gamma_cq = (const float*)d_in[7];
  const float* Wsq   = (const float*)d_in[8];
  const float* bsq   = (const float*)d_in[9];
  const float* Wbq   = (const float*)d_in[10];
  const float* gamma_ck = (const float*)d_in[11];
  const float* Wsk   = (const float*)d_in[12];
  const float* bsk   = (const float*)d_in[13];
  const float* Wbk   = (const float*)d_in[14];
  const float* Wq    = (const float*)d_in[15];
  const float* bq    = (const float*)d_in[16];
  const float* Wk    = (const float*)d_in[17];
  const float* Wv    = (const float*)d_in[18];
  const float* Wg    = (const float*)d_in[19];
  const float* Wt2   = (const float*)d_in[20];
  const float* Wzc   = (const float*)d_in[21];
  const float* bzc   = (const float*)d_in[22];

  char* wsb = (char*)d_ws;
  u16* WT     = (u16*)(wsb);                 // 10 x 32KB transposed bf16 weights
  u16* qbf    = (u16*)(wsb + 327680);        // [B,H,S,DH] bf16
  u16* kbf    = (u16*)(wsb + 1900544);       // [B,H,S,DH] bf16
  u16* vT     = (u16*)(wsb + 3473408);       // [B,H,DH,S] bf16
  float* gate = (float*)(wsb + 5046272);     // [B,S,C] f32
  float* zc   = (float*)(wsb + 8192000);     // [B,S,C] f32
  u16* wa     = (u16*)(wsb + 11337728);      // [B,S,C] bf16
  float* out  = (float*)d_out;

  PrepSrc ps;
  ps.p[0] = Wsq; ps.p[1] = Wbq; ps.p[2] = Wq; ps.p[3] = Wg; ps.p[4] = Wzc;
  ps.p[5] = Wsk; ps.p[6] = Wbk; ps.p[7] = Wk; ps.p[8] = Wv; ps.p[9] = Wt2;

  hipLaunchKernelGGL(prep, dim3(640), dim3(256), 0, stream, ps, WT);
  hipLaunchKernelGGL(rowblock_q, dim3(192), dim3(256), 0, stream,
                     x_q, scq, gamma_cq, bsq, bq, bzc, WT, qbf, gate, zc);
  hipLaunchKernelGGL(rowblock_k, dim3(192), dim3(256), 0, stream,
                     x_k, sck, gamma_ck, bsk, WT, kbf, vT);
  hipLaunchKernelGGL(attn, dim3(96, 8), dim3(128), 0, stream,
                     qbf, kbf, vT, pair, mask_q, mask_k, gate, wa);
  hipLaunchKernelGGL(finalk, dim3(192), dim3(256), 0, stream, wa, WT + 9 * 16384, zc, out);
}

// Round 2
// 149.824 us; speedup vs baseline: 1.0381x; 1.0381x over previous
//
#include <hip/hip_runtime.h>
#include <hip/hip_bf16.h>

typedef unsigned short u16;
typedef unsigned int u32;
typedef __attribute__((ext_vector_type(4))) float f32x4;
typedef __attribute__((ext_vector_type(4))) u32 u32x4;
typedef __attribute__((ext_vector_type(8))) __bf16 bf16x8;

#define SQ 3072
#define NH 4
#define DH 32
#define KSPLIT 4
#define KCHUNK (SQ / KSPLIT)  // 768

static __device__ __forceinline__ u16 f2bf(float f) {
  return __builtin_bit_cast(u16, (__bf16)f);
}
static __device__ __forceinline__ u32 pk2(float a, float b) {
  return (u32)f2bf(a) | ((u32)f2bf(b) << 16);
}
static __device__ __forceinline__ bf16x8 ld8(const u16* p) {
  return __builtin_bit_cast(bf16x8, *reinterpret_cast<const u32x4*>(p));
}
static __device__ __forceinline__ f32x4 mfma16(bf16x8 a, bf16x8 b, f32x4 c) {
  return __builtin_amdgcn_mfma_f32_16x16x32_bf16(a, b, c, 0, 0, 0);
}
static __device__ __forceinline__ float sigm(float x) { return 1.0f / (1.0f + __expf(-x)); }
static __device__ __forceinline__ float red8(float v) {
  v += __shfl_xor(v, 1); v += __shfl_xor(v, 2); v += __shfl_xor(v, 4);
  return v;
}

// A: 32x128 bf16 in LDS (row stride 136). B: WT[cout][k] bf16 (128x128, row stride 128).
static __device__ __forceinline__ void gemm32x128(
    const u16* a, const u16* wt, int lr, int lg, int wave, f32x4 d[2][2]) {
  f32x4 z = {0.f, 0.f, 0.f, 0.f};
  d[0][0] = z; d[0][1] = z; d[1][0] = z; d[1][1] = z;
#pragma unroll
  for (int kc = 0; kc < 4; ++kc) {
    int ko = kc * 32 + lg * 8;
    bf16x8 a0 = ld8(a + lr * 136 + ko);
    bf16x8 a1 = ld8(a + (16 + lr) * 136 + ko);
    bf16x8 b0 = ld8(wt + ((wave * 2 + 0) * 16 + lr) * 128 + ko);
    bf16x8 b1 = ld8(wt + ((wave * 2 + 1) * 16 + lr) * 128 + ko);
    d[0][0] = mfma16(a0, b0, d[0][0]);
    d[1][0] = mfma16(a1, b0, d[1][0]);
    d[0][1] = mfma16(a0, b1, d[0][1]);
    d[1][1] = mfma16(a1, b1, d[1][1]);
  }
}

struct PrepSrc { const float* p[10]; };

__global__ __launch_bounds__(256) void prep(PrepSrc s, u16* __restrict__ dst) {
  int bid = blockIdx.x;
  int mm = bid >> 6;
  int idx = ((bid & 63) << 8) + threadIdx.x;  // = cout*128 + k
  int co = idx >> 7, k = idx & 127;
  dst[mm * 16384 + idx] = f2bf(s.p[mm][k * 128 + co]);
}

__global__ __launch_bounds__(256) void rowblock_q(
    const float* __restrict__ x, const float* __restrict__ cond,
    const float* __restrict__ gamma, const float* __restrict__ bs,
    const float* __restrict__ bq, const float* __restrict__ bzc,
    const u16* __restrict__ WT,
    u16* __restrict__ qbf, float* __restrict__ gate, float* __restrict__ zc) {
  __shared__ float xnf[32 * 132];
  __shared__ u16 a_cn[32 * 136];
  __shared__ u16 a_raw[32 * 136];
  __shared__ u16 a_xa[32 * 136];
  const int tid = threadIdx.x;
  const int rl = tid >> 3, sub = tid & 7, c0 = sub * 16;
  const size_t grow = (size_t)blockIdx.x * 32 + rl;

  {
    float xs[16];
    const float4* xr = reinterpret_cast<const float4*>(x + grow * 128 + c0);
#pragma unroll
    for (int i = 0; i < 4; ++i) { float4 t = xr[i]; xs[4*i]=t.x; xs[4*i+1]=t.y; xs[4*i+2]=t.z; xs[4*i+3]=t.w; }
    float s = 0.f;
#pragma unroll
    for (int i = 0; i < 16; ++i) s += xs[i];
    float mean = red8(s) * (1.f / 128.f);
    float vs = 0.f;
#pragma unroll
    for (int i = 0; i < 16; ++i) { float dd = xs[i] - mean; vs += dd * dd; }
    float rstd = rsqrtf(red8(vs) * (1.f / 128.f) + 1e-5f);
    float4* xw = reinterpret_cast<float4*>(&xnf[rl * 132 + c0]);
#pragma unroll
    for (int i = 0; i < 4; ++i) {
      float4 t;
      t.x = (xs[4*i+0] - mean) * rstd; t.y = (xs[4*i+1] - mean) * rstd;
      t.z = (xs[4*i+2] - mean) * rstd; t.w = (xs[4*i+3] - mean) * rstd;
      xw[i] = t;
    }
  }
  {
    float cs[16], gs[16];
    const float4* cr = reinterpret_cast<const float4*>(cond + grow * 128 + c0);
    const float4* gr = reinterpret_cast<const float4*>(gamma + c0);
#pragma unroll
    for (int i = 0; i < 4; ++i) { float4 t = cr[i]; cs[4*i]=t.x; cs[4*i+1]=t.y; cs[4*i+2]=t.z; cs[4*i+3]=t.w; }
#pragma unroll
    for (int i = 0; i < 4; ++i) { float4 t = gr[i]; gs[4*i]=t.x; gs[4*i+1]=t.y; gs[4*i+2]=t.z; gs[4*i+3]=t.w; }
    float s = 0.f;
#pragma unroll
    for (int i = 0; i < 16; ++i) s += cs[i];
    float mean = red8(s) * (1.f / 128.f);
    float vs = 0.f;
#pragma unroll
    for (int i = 0; i < 16; ++i) { float dd = cs[i] - mean; vs += dd * dd; }
    float rstd = rsqrtf(red8(vs) * (1.f / 128.f) + 1e-5f);
    float cn[16];
#pragma unroll
    for (int i = 0; i < 16; ++i) cn[i] = (cs[i] - mean) * rstd * gs[i];
    u32x4* cw = reinterpret_cast<u32x4*>(&a_cn[rl * 136 + c0]);
    u32x4 w0 = {pk2(cn[0],cn[1]), pk2(cn[2],cn[3]), pk2(cn[4],cn[5]), pk2(cn[6],cn[7])};
    u32x4 w1 = {pk2(cn[8],cn[9]), pk2(cn[10],cn[11]), pk2(cn[12],cn[13]), pk2(cn[14],cn[15])};
    cw[0] = w0; cw[1] = w1;
    u32x4* rw = reinterpret_cast<u32x4*>(&a_raw[rl * 136 + c0]);
    u32x4 r0 = {pk2(cs[0],cs[1]), pk2(cs[2],cs[3]), pk2(cs[4],cs[5]), pk2(cs[6],cs[7])};
    u32x4 r1 = {pk2(cs[8],cs[9]), pk2(cs[10],cs[11]), pk2(cs[12],cs[13]), pk2(cs[14],cs[15])};
    rw[0] = r0; rw[1] = r1;
  }
  __syncthreads();
  const int lane = tid & 63, wave = tid >> 6, lr = lane & 15, lg = lane >> 4;
  f32x4 dS[2][2], dB[2][2];
  gemm32x128(a_cn, WT + 0 * 16384, lr, lg, wave, dS);
  gemm32x128(a_cn, WT + 1 * 16384, lr, lg, wave, dB);
#pragma unroll
  for (int mt = 0; mt < 2; ++mt)
#pragma unroll
    for (int j = 0; j < 2; ++j)
#pragma unroll
      for (int r = 0; r < 4; ++r) {
        int col = (wave * 2 + j) * 16 + lr;
        int rowl = mt * 16 + lg * 4 + r;
        float sc = dS[mt][j][r] + bs[col];
        float xa = sigm(sc) * xnf[rowl * 132 + col] + dB[mt][j][r];
        a_xa[rowl * 136 + col] = f2bf(xa);
      }
  __syncthreads();
  f32x4 dQ[2][2], dG[2][2], dZ[2][2];
  gemm32x128(a_xa, WT + 2 * 16384, lr, lg, wave, dQ);
  gemm32x128(a_xa, WT + 3 * 16384, lr, lg, wave, dG);
  gemm32x128(a_raw, WT + 4 * 16384, lr, lg, wave, dZ);
#pragma unroll
  for (int mt = 0; mt < 2; ++mt)
#pragma unroll
    for (int j = 0; j < 2; ++j)
#pragma unroll
      for (int r = 0; r < 4; ++r) {
        int col = (wave * 2 + j) * 16 + lr;
        int rowl = mt * 16 + lg * 4 + r;
        size_t gr = (size_t)blockIdx.x * 32 + rowl;
        int b = (int)(gr >= SQ);
        int pos = (int)gr - b * SQ;
        float qv = (dQ[mt][j][r] + bq[col]) * 0.17677669529663687f;  // Dh^-0.5
        qbf[(((size_t)b * NH + (col >> 5)) * SQ + pos) * DH + (col & 31)] = f2bf(qv);
        gate[gr * 128 + col] = sigm(dG[mt][j][r]);
        zc[gr * 128 + col] = sigm(dZ[mt][j][r] + bzc[col]);
      }
}

__global__ __launch_bounds__(256) void rowblock_k(
    const float* __restrict__ x, const float* __restrict__ cond,
    const float* __restrict__ gamma, const float* __restrict__ bs,
    const u16* __restrict__ WT,
    u16* __restrict__ kbf, u16* __restrict__ vT) {
  __shared__ float xnf[32 * 132];
  __shared__ u16 a_cn[32 * 136];
  __shared__ u16 a_xa[32 * 136];
  const int tid = threadIdx.x;
  const int rl = tid >> 3, sub = tid & 7, c0 = sub * 16;
  const size_t grow = (size_t)blockIdx.x * 32 + rl;
  {
    float xs[16];
    const float4* xr = reinterpret_cast<const float4*>(x + grow * 128 + c0);
#pragma unroll
    for (int i = 0; i < 4; ++i) { float4 t = xr[i]; xs[4*i]=t.x; xs[4*i+1]=t.y; xs[4*i+2]=t.z; xs[4*i+3]=t.w; }
    float s = 0.f;
#pragma unroll
    for (int i = 0; i < 16; ++i) s += xs[i];
    float mean = red8(s) * (1.f / 128.f);
    float vs = 0.f;
#pragma unroll
    for (int i = 0; i < 16; ++i) { float dd = xs[i] - mean; vs += dd * dd; }
    float rstd = rsqrtf(red8(vs) * (1.f / 128.f) + 1e-5f);
    float4* xw = reinterpret_cast<float4*>(&xnf[rl * 132 + c0]);
#pragma unroll
    for (int i = 0; i < 4; ++i) {
      float4 t;
      t.x = (xs[4*i+0] - mean) * rstd; t.y = (xs[4*i+1] - mean) * rstd;
      t.z = (xs[4*i+2] - mean) * rstd; t.w = (xs[4*i+3] - mean) * rstd;
      xw[i] = t;
    }
  }
  {
    float cs[16], gs[16];
    const float4* cr = reinterpret_cast<const float4*>(cond + grow * 128 + c0);
    const float4* gr = reinterpret_cast<const float4*>(gamma + c0);
#pragma unroll
    for (int i = 0; i < 4; ++i) { float4 t = cr[i]; cs[4*i]=t.x; cs[4*i+1]=t.y; cs[4*i+2]=t.z; cs[4*i+3]=t.w; }
#pragma unroll
    for (int i = 0; i < 4; ++i) { float4 t = gr[i]; gs[4*i]=t.x; gs[4*i+1]=t.y; gs[4*i+2]=t.z; gs[4*i+3]=t.w; }
    float s = 0.f;
#pragma unroll
    for (int i = 0; i < 16; ++i) s += cs[i];
    float mean = red8(s) * (1.f / 128.f);
    float vs = 0.f;
#pragma unroll
    for (int i = 0; i < 16; ++i) { float dd = cs[i] - mean; vs += dd * dd; }
    float rstd = rsqrtf(red8(vs) * (1.f / 128.f) + 1e-5f);
    float cn[16];
#pragma unroll
    for (int i = 0; i < 16; ++i) cn[i] = (cs[i] - mean) * rstd * gs[i];
    u32x4* cw = reinterpret_cast<u32x4*>(&a_cn[rl * 136 + c0]);
    u32x4 w0 = {pk2(cn[0],cn[1]), pk2(cn[2],cn[3]), pk2(cn[4],cn[5]), pk2(cn[6],cn[7])};
    u32x4 w1 = {pk2(cn[8],cn[9]), pk2(cn[10],cn[11]), pk2(cn[12],cn[13]), pk2(cn[14],cn[15])};
    cw[0] = w0; cw[1] = w1;
  }
  __syncthreads();
  const int lane = tid & 63, wave = tid >> 6, lr = lane & 15, lg = lane >> 4;
  f32x4 dS[2][2], dB[2][2];
  gemm32x128(a_cn, WT + 5 * 16384, lr, lg, wave, dS);
  gemm32x128(a_cn, WT + 6 * 16384, lr, lg, wave, dB);
#pragma unroll
  for (int mt = 0; mt < 2; ++mt)
#pragma unroll
    for (int j = 0; j < 2; ++j)
#pragma unroll
      for (int r = 0; r < 4; ++r) {
        int col = (wave * 2 + j) * 16 + lr;
        int rowl = mt * 16 + lg * 4 + r;
        float sc = dS[mt][j][r] + bs[col];
        float xa = sigm(sc) * xnf[rowl * 132 + col] + dB[mt][j][r];
        a_xa[rowl * 136 + col] = f2bf(xa);
      }
  __syncthreads();
  f32x4 dK[2][2], dV[2][2];
  gemm32x128(a_xa, WT + 7 * 16384, lr, lg, wave, dK);
  gemm32x128(a_xa, WT + 8 * 16384, lr, lg, wave, dV);
#pragma unroll
  for (int mt = 0; mt < 2; ++mt)
#pragma unroll
    for (int j = 0; j < 2; ++j)
#pragma unroll
      for (int r = 0; r < 4; ++r) {
        int col = (wave * 2 + j) * 16 + lr;
        int rowl = mt * 16 + lg * 4 + r;
        size_t gr = (size_t)blockIdx.x * 32 + rowl;
        int b = (int)(gr >= SQ);
        int pos = (int)gr - b * SQ;
        int h = col >> 5, dd = col & 31;
        kbf[(((size_t)b * NH + h) * SQ + pos) * DH + dd] = f2bf(dK[mt][j][r]);
        vT[(((size_t)b * NH + h) * DH + dd) * SQ + pos] = f2bf(dV[mt][j][r]);
      }
}

static __device__ __forceinline__ void ldpair(const float* prow, int col0, int lr, float* dst) {
#pragma unroll
  for (int kt = 0; kt < 4; ++kt)
#pragma unroll
    for (int r = 0; r < 4; ++r)
      dst[kt * 4 + r] =
          __builtin_nontemporal_load(prow + (size_t)r * SQ + col0 + kt * 16 + lr);
}

// Flash attention with split-K: one wave = 16 q rows, KCHUNK keys, online softmax.
// Writes unnormalized partials (o, m, l) per split; merge kernel combines.
__global__ __launch_bounds__(128) void attn(
    const u16* __restrict__ qbf, const u16* __restrict__ kbf, const u16* __restrict__ vT,
    const float* __restrict__ pair, const int* __restrict__ mask_q,
    const int* __restrict__ mask_k,
    float* __restrict__ part_o, float* __restrict__ part_m, float* __restrict__ part_l) {
  __shared__ u16 plds[2][16 * 72];
  const int tid = threadIdx.x, lane = tid & 63, wave = tid >> 6, lr = lane & 15, lg = lane >> 4;
  const int bh = blockIdx.y, b = bh >> 2;
  const int q0 = blockIdx.x * 32 + wave * 16;
  const int k0 = blockIdx.z * KCHUNK, kend = k0 + KCHUNK;
  const bf16x8 aq = ld8(qbf + ((size_t)bh * SQ + q0 + lr) * DH + lg * 8);
  float mqm1[4];
#pragma unroll
  for (int r = 0; r < 4; ++r)
    mqm1[r] = 1e9f * ((float)mask_q[b * SQ + q0 + lg * 4 + r] - 1.f);
  float m[4], l[4];
#pragma unroll
  for (int r = 0; r < 4; ++r) { m[r] = -1e30f; l[r] = 0.f; }
  const f32x4 zero = {0.f, 0.f, 0.f, 0.f};
  f32x4 o[2]; o[0] = zero; o[1] = zero;
  const float* prow = pair + ((size_t)bh * SQ + q0 + lg * 4) * SQ;
  u16* pw = plds[wave];
  float pv[16], pn[16];
  ldpair(prow, k0, lr, pv);
  for (int kb = k0; kb < kend; kb += 64) {
    const bool more = (kb + 64) < kend;  // wave-uniform
    if (more) ldpair(prow, kb + 64, lr, pn);  // prefetch next step's pair block
    f32x4 s[4];
#pragma unroll
    for (int kt = 0; kt < 4; ++kt)
      s[kt] = mfma16(aq, ld8(kbf + ((size_t)bh * SQ + kb + kt * 16 + lr) * DH + lg * 8), zero);
    float mk1[4];
#pragma unroll
    for (int kt = 0; kt < 4; ++kt)
      mk1[kt] = (float)mask_k[b * SQ + kb + kt * 16 + lr] - 1.f;
#pragma unroll
    for (int kt = 0; kt < 4; ++kt)
#pragma unroll
      for (int r = 0; r < 4; ++r)
        s[kt][r] += fmaf(mqm1[r], mk1[kt], pv[kt * 4 + r]);  // exact-1e9 masking preserved
    float alpha[4];
#pragma unroll
    for (int r = 0; r < 4; ++r) {
      float mx = fmaxf(fmaxf(s[0][r], s[1][r]), fmaxf(s[2][r], s[3][r]));
      mx = fmaxf(mx, __shfl_xor(mx, 1));
      mx = fmaxf(mx, __shfl_xor(mx, 2));
      mx = fmaxf(mx, __shfl_xor(mx, 4));
      mx = fmaxf(mx, __shfl_xor(mx, 8));
      float mn = fmaxf(m[r], mx);
      alpha[r] = __expf(m[r] - mn);
      m[r] = mn;
    }
#pragma unroll
    for (int r = 0; r < 4; ++r) {
      float acc = 0.f;
#pragma unroll
      for (int kt = 0; kt < 4; ++kt) {
        float p = __expf(s[kt][r] - m[r]);
        s[kt][r] = p;
        acc += p;
      }
      acc += __shfl_xor(acc, 1); acc += __shfl_xor(acc, 2);
      acc += __shfl_xor(acc, 4); acc += __shfl_xor(acc, 8);
      l[r] = l[r] * alpha[r] + acc;
      o[0][r] *= alpha[r];
      o[1][r] *= alpha[r];
    }
#pragma unroll
    for (int kt = 0; kt < 4; ++kt)
#pragma unroll
      for (int r = 0; r < 4; ++r)
        pw[(lg * 4 + r) * 72 + kt * 16 + lr] = f2bf(s[kt][r]);
#pragma unroll
    for (int kc = 0; kc < 2; ++kc) {
      bf16x8 pa = ld8(pw + lr * 72 + kc * 32 + lg * 8);
#pragma unroll
      for (int hf = 0; hf < 2; ++hf) {
        bf16x8 bv = ld8(vT + ((size_t)bh * DH + hf * 16 + lr) * SQ + kb + kc * 32 + lg * 8);
        o[hf] = mfma16(pa, bv, o[hf]);
      }
    }
    if (more) {
#pragma unroll
      for (int i = 0; i < 16; ++i) pv[i] = pn[i];
    }
  }
  const int zbase = (blockIdx.z * 8 + bh) * SQ;
#pragma unroll
  for (int r = 0; r < 4; ++r) {
    int q = q0 + lg * 4 + r;
    if (lr == 0) {  // m,l uniform across the 16-lane group
      part_m[zbase + q] = m[r];
      part_l[zbase + q] = l[r];
    }
#pragma unroll
    for (int hf = 0; hf < 2; ++hf)
      part_o[((size_t)(zbase + q)) * 32 + hf * 16 + lr] = o[hf][r];
  }
}

// Combine KSPLIT partials, normalize, apply gate, write wa (bf16).
__global__ __launch_bounds__(256) void merge(
    const float* __restrict__ part_o, const float* __restrict__ part_m,
    const float* __restrict__ part_l, const float* __restrict__ gate,
    u16* __restrict__ wa) {
  const int idx = blockIdx.x * 256 + threadIdx.x;  // < 8*SQ*32
  const int c = idx & 31;
  const int row = idx >> 5;  // bh*SQ + q
  float mv[KSPLIT];
  float mm = -1e30f;
#pragma unroll
  for (int z = 0; z < KSPLIT; ++z) {
    mv[z] = part_m[z * 8 * SQ + row];
    mm = fmaxf(mm, mv[z]);
  }
  float l = 0.f, o = 0.f;
#pragma unroll
  for (int z = 0; z < KSPLIT; ++z) {
    float w = __expf(mv[z] - mm);
    l = fmaf(w, part_l[z * 8 * SQ + row], l);
    o = fmaf(w, part_o[((size_t)(z * 8 * SQ + row)) * 32 + c], o);
  }
  const int bh = row / SQ, q = row - bh * SQ;
  const int b = bh >> 2, h = bh & 3;
  const size_t gi = ((size_t)b * SQ + q) * 128 + h * 32 + c;
  wa[gi] = f2bf((o / l) * gate[gi]);
}

// out = (wa @ Wt2) * zc
__global__ __launch_bounds__(256) void finalk(
    const u16* __restrict__ wa, const u16* __restrict__ WTt2,
    const float* __restrict__ zc, float* __restrict__ out) {
  __shared__ u16 awa[32 * 136];
  const int tid = threadIdx.x, rl = tid >> 3, sub = tid & 7, c0 = sub * 16;
  const size_t grow = (size_t)blockIdx.x * 32 + rl;
  const u32x4* srcp = reinterpret_cast<const u32x4*>(wa + grow * 128 + c0);
  u32x4* dstp = reinterpret_cast<u32x4*>(&awa[rl * 136 + c0]);
  dstp[0] = srcp[0];
  dstp[1] = srcp[1];
  __syncthreads();
  const int lane = tid & 63, wave = tid >> 6, lr = lane & 15, lg = lane >> 4;
  f32x4 d[2][2];
  gemm32x128(awa, WTt2, lr, lg, wave, d);
#pragma unroll
  for (int mt = 0; mt < 2; ++mt)
#pragma unroll
    for (int j = 0; j < 2; ++j)
#pragma unroll
      for (int r = 0; r < 4; ++r) {
        int col = (wave * 2 + j) * 16 + lr;
        size_t gr = (size_t)blockIdx.x * 32 + mt * 16 + lg * 4 + r;
        out[gr * 128 + col] = d[mt][j][r] * zc[gr * 128 + col];
      }
}

extern "C" void kernel_launch(void* const* d_in, const int* in_sizes, int n_in,
                              void* d_out, int out_size, void* d_ws, size_t ws_size,
                              hipStream_t stream) {
  const float* x_q   = (const float*)d_in[0];
  const float* x_k   = (const float*)d_in[1];
  const int* mask_q  = (const int*)d_in[2];
  const int* mask_k  = (const int*)d_in[3];
  const float* pair  = (const float*)d_in[4];
  const float* scq   = (const float*)d_in[5];
  const float* sck   = (const float*)d_in[6];
  const float* gamma_cq = (const float*)d_in[7];
  const float* Wsq   = (const float*)d_in[8];
  const float* bsq   = (const float*)d_in[9];
  const float* Wbq   = (const float*)d_in[10];
  const float* gamma_ck = (const float*)d_in[11];
  const float* Wsk   = (const float*)d_in[12];
  const float* bsk   = (const float*)d_in[13];
  const float* Wbk   = (const float*)d_in[14];
  const float* Wq    = (const float*)d_in[15];
  const float* bq    = (const float*)d_in[16];
  const float* Wk    = (const float*)d_in[17];
  const float* Wv    = (const float*)d_in[18];
  const float* Wg    = (const float*)d_in[19];
  const float* Wt2   = (const float*)d_in[20];
  const float* Wzc   = (const float*)d_in[21];
  const float* bzc   = (const float*)d_in[22];

  char* wsb = (char*)d_ws;
  u16* WT       = (u16*)(wsb);               // 10 x 32KB transposed bf16 weights
  u16* qbf      = (u16*)(wsb + 327680);      // [B,H,S,DH] bf16
  u16* kbf      = (u16*)(wsb + 1900544);     // [B,H,S,DH] bf16
  u16* vT       = (u16*)(wsb + 3473408);     // [B,H,DH,S] bf16
  float* gate   = (float*)(wsb + 5046272);   // [B,S,C] f32
  float* zc     = (float*)(wsb + 8192000);   // [B,S,C] f32
  u16* wa       = (u16*)(wsb + 11337728);    // [B,S,C] bf16 (ends 12910592)
  float* part_o = (float*)(wsb + 12910592);  // [KSPLIT,8,SQ,32] f32 (12.6 MB)
  float* part_m = (float*)(wsb + 25493504);  // [KSPLIT,8,SQ] f32
  float* part_l = (float*)(wsb + 25886720);  // [KSPLIT,8,SQ] f32
  float* out    = (float*)d_out;

  PrepSrc ps;
  ps.p[0] = Wsq; ps.p[1] = Wbq; ps.p[2] = Wq; ps.p[3] = Wg; ps.p[4] = Wzc;
  ps.p[5] = Wsk; ps.p[6] = Wbk; ps.p[7] = Wk; ps.p[8] = Wv; ps.p[9] = Wt2;

  hipLaunchKernelGGL(prep, dim3(640), dim3(256), 0, stream, ps, WT);
  hipLaunchKernelGGL(rowblock_q, dim3(192), dim3(256), 0, stream,
                     x_q, scq, gamma_cq, bsq, bq, bzc, WT, qbf, gate, zc);
  hipLaunchKernelGGL(rowblock_k, dim3(192), dim3(256), 0, stream,
                     x_k, sck, gamma_ck, bsk, WT, kbf, vT);
  hipLaunchKernelGGL(attn, dim3(96, 8, KSPLIT), dim3(128), 0, stream,
                     qbf, kbf, vT, pair, mask_q, mask_k, part_o, part_m, part_l);
  hipLaunchKernelGGL(merge, dim3(8 * SQ * 32 / 256), dim3(256), 0, stream,
                     part_o, part_m, part_l, gate, wa);
  hipLaunchKernelGGL(finalk, dim3(192), dim3(256), 0, stream, wa, WT + 9 * 16384, zc, out);
}

// Round 4
// 130.399 us; speedup vs baseline: 1.1927x; 1.1490x over previous
//
#include <hip/hip_runtime.h>
#include <hip/hip_bf16.h>

typedef unsigned short u16;
typedef unsigned int u32;
typedef __attribute__((ext_vector_type(4))) float f32x4;
typedef __attribute__((ext_vector_type(4))) u32 u32x4;
typedef __attribute__((ext_vector_type(8))) __bf16 bf16x8;

#define SQ 3072
#define NH 4
#define DH 32
#define KSPLIT 4
#define KCHUNK (SQ / KSPLIT)  // 768

static __device__ __forceinline__ u16 f2bf(float f) {
  return __builtin_bit_cast(u16, (__bf16)f);
}
static __device__ __forceinline__ u32 pk2(float a, float b) {
  return (u32)f2bf(a) | ((u32)f2bf(b) << 16);
}
static __device__ __forceinline__ bf16x8 ld8(const u16* p) {
  return __builtin_bit_cast(bf16x8, *reinterpret_cast<const u32x4*>(p));
}
static __device__ __forceinline__ f32x4 mfma16(bf16x8 a, bf16x8 b, f32x4 c) {
  return __builtin_amdgcn_mfma_f32_16x16x32_bf16(a, b, c, 0, 0, 0);
}
static __device__ __forceinline__ float sigm(float x) { return 1.0f / (1.0f + __expf(-x)); }
static __device__ __forceinline__ float red8(float v) {
  v += __shfl_xor(v, 1); v += __shfl_xor(v, 2); v += __shfl_xor(v, 4);
  return v;
}

// A: 32x128 bf16 in LDS (row stride 136). B: WT[cout][k] bf16 (128x128, row stride 128).
static __device__ __forceinline__ void gemm32x128(
    const u16* a, const u16* wt, int lr, int lg, int wave, f32x4 d[2][2]) {
  f32x4 z = {0.f, 0.f, 0.f, 0.f};
  d[0][0] = z; d[0][1] = z; d[1][0] = z; d[1][1] = z;
#pragma unroll
  for (int kc = 0; kc < 4; ++kc) {
    int ko = kc * 32 + lg * 8;
    bf16x8 a0 = ld8(a + lr * 136 + ko);
    bf16x8 a1 = ld8(a + (16 + lr) * 136 + ko);
    bf16x8 b0 = ld8(wt + ((wave * 2 + 0) * 16 + lr) * 128 + ko);
    bf16x8 b1 = ld8(wt + ((wave * 2 + 1) * 16 + lr) * 128 + ko);
    d[0][0] = mfma16(a0, b0, d[0][0]);
    d[1][0] = mfma16(a1, b0, d[1][0]);
    d[0][1] = mfma16(a0, b1, d[0][1]);
    d[1][1] = mfma16(a1, b1, d[1][1]);
  }
}

struct PrepSrc { const float* p[10]; };

__global__ __launch_bounds__(256) void prep(PrepSrc s, u16* __restrict__ dst) {
  int bid = blockIdx.x;
  int mm = bid >> 6;
  int idx = ((bid & 63) << 8) + threadIdx.x;  // = cout*128 + k
  int co = idx >> 7, k = idx & 127;
  dst[mm * 16384 + idx] = f2bf(s.p[mm][k * 128 + co]);
}

__global__ __launch_bounds__(256) void rowblock_q(
    const float* __restrict__ x, const float* __restrict__ cond,
    const float* __restrict__ gamma, const float* __restrict__ bs,
    const float* __restrict__ bq, const float* __restrict__ bzc,
    const u16* __restrict__ WT,
    u16* __restrict__ qbf, float* __restrict__ gate, float* __restrict__ zc) {
  __shared__ float xnf[32 * 132];
  __shared__ u16 a_cn[32 * 136];
  __shared__ u16 a_raw[32 * 136];
  __shared__ u16 a_xa[32 * 136];
  const int tid = threadIdx.x;
  const int rl = tid >> 3, sub = tid & 7, c0 = sub * 16;
  const size_t grow = (size_t)blockIdx.x * 32 + rl;

  {
    float xs[16];
    const float4* xr = reinterpret_cast<const float4*>(x + grow * 128 + c0);
#pragma unroll
    for (int i = 0; i < 4; ++i) { float4 t = xr[i]; xs[4*i]=t.x; xs[4*i+1]=t.y; xs[4*i+2]=t.z; xs[4*i+3]=t.w; }
    float s = 0.f;
#pragma unroll
    for (int i = 0; i < 16; ++i) s += xs[i];
    float mean = red8(s) * (1.f / 128.f);
    float vs = 0.f;
#pragma unroll
    for (int i = 0; i < 16; ++i) { float dd = xs[i] - mean; vs += dd * dd; }
    float rstd = rsqrtf(red8(vs) * (1.f / 128.f) + 1e-5f);
    float4* xw = reinterpret_cast<float4*>(&xnf[rl * 132 + c0]);
#pragma unroll
    for (int i = 0; i < 4; ++i) {
      float4 t;
      t.x = (xs[4*i+0] - mean) * rstd; t.y = (xs[4*i+1] - mean) * rstd;
      t.z = (xs[4*i+2] - mean) * rstd; t.w = (xs[4*i+3] - mean) * rstd;
      xw[i] = t;
    }
  }
  {
    float cs[16], gs[16];
    const float4* cr = reinterpret_cast<const float4*>(cond + grow * 128 + c0);
    const float4* gr = reinterpret_cast<const float4*>(gamma + c0);
#pragma unroll
    for (int i = 0; i < 4; ++i) { float4 t = cr[i]; cs[4*i]=t.x; cs[4*i+1]=t.y; cs[4*i+2]=t.z; cs[4*i+3]=t.w; }
#pragma unroll
    for (int i = 0; i < 4; ++i) { float4 t = gr[i]; gs[4*i]=t.x; gs[4*i+1]=t.y; gs[4*i+2]=t.z; gs[4*i+3]=t.w; }
    float s = 0.f;
#pragma unroll
    for (int i = 0; i < 16; ++i) s += cs[i];
    float mean = red8(s) * (1.f / 128.f);
    float vs = 0.f;
#pragma unroll
    for (int i = 0; i < 16; ++i) { float dd = cs[i] - mean; vs += dd * dd; }
    float rstd = rsqrtf(red8(vs) * (1.f / 128.f) + 1e-5f);
    float cn[16];
#pragma unroll
    for (int i = 0; i < 16; ++i) cn[i] = (cs[i] - mean) * rstd * gs[i];
    u32x4* cw = reinterpret_cast<u32x4*>(&a_cn[rl * 136 + c0]);
    u32x4 w0 = {pk2(cn[0],cn[1]), pk2(cn[2],cn[3]), pk2(cn[4],cn[5]), pk2(cn[6],cn[7])};
    u32x4 w1 = {pk2(cn[8],cn[9]), pk2(cn[10],cn[11]), pk2(cn[12],cn[13]), pk2(cn[14],cn[15])};
    cw[0] = w0; cw[1] = w1;
    u32x4* rw = reinterpret_cast<u32x4*>(&a_raw[rl * 136 + c0]);
    u32x4 r0 = {pk2(cs[0],cs[1]), pk2(cs[2],cs[3]), pk2(cs[4],cs[5]), pk2(cs[6],cs[7])};
    u32x4 r1 = {pk2(cs[8],cs[9]), pk2(cs[10],cs[11]), pk2(cs[12],cs[13]), pk2(cs[14],cs[15])};
    rw[0] = r0; rw[1] = r1;
  }
  __syncthreads();
  const int lane = tid & 63, wave = tid >> 6, lr = lane & 15, lg = lane >> 4;
  f32x4 dS[2][2], dB[2][2];
  gemm32x128(a_cn, WT + 0 * 16384, lr, lg, wave, dS);
  gemm32x128(a_cn, WT + 1 * 16384, lr, lg, wave, dB);
#pragma unroll
  for (int mt = 0; mt < 2; ++mt)
#pragma unroll
    for (int j = 0; j < 2; ++j)
#pragma unroll
      for (int r = 0; r < 4; ++r) {
        int col = (wave * 2 + j) * 16 + lr;
        int rowl = mt * 16 + lg * 4 + r;
        float sc = dS[mt][j][r] + bs[col];
        float xa = sigm(sc) * xnf[rowl * 132 + col] + dB[mt][j][r];
        a_xa[rowl * 136 + col] = f2bf(xa);
      }
  __syncthreads();
  f32x4 dQ[2][2], dG[2][2], dZ[2][2];
  gemm32x128(a_xa, WT + 2 * 16384, lr, lg, wave, dQ);
  gemm32x128(a_xa, WT + 3 * 16384, lr, lg, wave, dG);
  gemm32x128(a_raw, WT + 4 * 16384, lr, lg, wave, dZ);
#pragma unroll
  for (int mt = 0; mt < 2; ++mt)
#pragma unroll
    for (int j = 0; j < 2; ++j)
#pragma unroll
      for (int r = 0; r < 4; ++r) {
        int col = (wave * 2 + j) * 16 + lr;
        int rowl = mt * 16 + lg * 4 + r;
        size_t gr = (size_t)blockIdx.x * 32 + rowl;
        int b = (int)(gr >= SQ);
        int pos = (int)gr - b * SQ;
        float qv = (dQ[mt][j][r] + bq[col]) * 0.17677669529663687f;  // Dh^-0.5
        qbf[(((size_t)b * NH + (col >> 5)) * SQ + pos) * DH + (col & 31)] = f2bf(qv);
        gate[gr * 128 + col] = sigm(dG[mt][j][r]);
        zc[gr * 128 + col] = sigm(dZ[mt][j][r] + bzc[col]);
      }
}

__global__ __launch_bounds__(256) void rowblock_k(
    const float* __restrict__ x, const float* __restrict__ cond,
    const float* __restrict__ gamma, const float* __restrict__ bs,
    const u16* __restrict__ WT,
    u16* __restrict__ kbf, u16* __restrict__ vT) {
  __shared__ float xnf[32 * 132];
  __shared__ u16 a_cn[32 * 136];
  __shared__ u16 a_xa[32 * 136];
  const int tid = threadIdx.x;
  const int rl = tid >> 3, sub = tid & 7, c0 = sub * 16;
  const size_t grow = (size_t)blockIdx.x * 32 + rl;
  {
    float xs[16];
    const float4* xr = reinterpret_cast<const float4*>(x + grow * 128 + c0);
#pragma unroll
    for (int i = 0; i < 4; ++i) { float4 t = xr[i]; xs[4*i]=t.x; xs[4*i+1]=t.y; xs[4*i+2]=t.z; xs[4*i+3]=t.w; }
    float s = 0.f;
#pragma unroll
    for (int i = 0; i < 16; ++i) s += xs[i];
    float mean = red8(s) * (1.f / 128.f);
    float vs = 0.f;
#pragma unroll
    for (int i = 0; i < 16; ++i) { float dd = xs[i] - mean; vs += dd * dd; }
    float rstd = rsqrtf(red8(vs) * (1.f / 128.f) + 1e-5f);
    float4* xw = reinterpret_cast<float4*>(&xnf[rl * 132 + c0]);
#pragma unroll
    for (int i = 0; i < 4; ++i) {
      float4 t;
      t.x = (xs[4*i+0] - mean) * rstd; t.y = (xs[4*i+1] - mean) * rstd;
      t.z = (xs[4*i+2] - mean) * rstd; t.w = (xs[4*i+3] - mean) * rstd;
      xw[i] = t;
    }
  }
  {
    float cs[16], gs[16];
    const float4* cr = reinterpret_cast<const float4*>(cond + grow * 128 + c0);
    const float4* gr = reinterpret_cast<const float4*>(gamma + c0);
#pragma unroll
    for (int i = 0; i < 4; ++i) { float4 t = cr[i]; cs[4*i]=t.x; cs[4*i+1]=t.y; cs[4*i+2]=t.z; cs[4*i+3]=t.w; }
#pragma unroll
    for (int i = 0; i < 4; ++i) { float4 t = gr[i]; gs[4*i]=t.x; gs[4*i+1]=t.y; gs[4*i+2]=t.z; gs[4*i+3]=t.w; }
    float s = 0.f;
#pragma unroll
    for (int i = 0; i < 16; ++i) s += cs[i];
    float mean = red8(s) * (1.f / 128.f);
    float vs = 0.f;
#pragma unroll
    for (int i = 0; i < 16; ++i) { float dd = cs[i] - mean; vs += dd * dd; }
    float rstd = rsqrtf(red8(vs) * (1.f / 128.f) + 1e-5f);
    float cn[16];
#pragma unroll
    for (int i = 0; i < 16; ++i) cn[i] = (cs[i] - mean) * rstd * gs[i];
    u32x4* cw = reinterpret_cast<u32x4*>(&a_cn[rl * 136 + c0]);
    u32x4 w0 = {pk2(cn[0],cn[1]), pk2(cn[2],cn[3]), pk2(cn[4],cn[5]), pk2(cn[6],cn[7])};
    u32x4 w1 = {pk2(cn[8],cn[9]), pk2(cn[10],cn[11]), pk2(cn[12],cn[13]), pk2(cn[14],cn[15])};
    cw[0] = w0; cw[1] = w1;
  }
  __syncthreads();
  const int lane = tid & 63, wave = tid >> 6, lr = lane & 15, lg = lane >> 4;
  f32x4 dS[2][2], dB[2][2];
  gemm32x128(a_cn, WT + 5 * 16384, lr, lg, wave, dS);
  gemm32x128(a_cn, WT + 6 * 16384, lr, lg, wave, dB);
#pragma unroll
  for (int mt = 0; mt < 2; ++mt)
#pragma unroll
    for (int j = 0; j < 2; ++j)
#pragma unroll
      for (int r = 0; r < 4; ++r) {
        int col = (wave * 2 + j) * 16 + lr;
        int rowl = mt * 16 + lg * 4 + r;
        float sc = dS[mt][j][r] + bs[col];
        float xa = sigm(sc) * xnf[rowl * 132 + col] + dB[mt][j][r];
        a_xa[rowl * 136 + col] = f2bf(xa);
      }
  __syncthreads();
  f32x4 dK[2][2], dV[2][2];
  gemm32x128(a_xa, WT + 7 * 16384, lr, lg, wave, dK);
  gemm32x128(a_xa, WT + 8 * 16384, lr, lg, wave, dV);
#pragma unroll
  for (int mt = 0; mt < 2; ++mt)
#pragma unroll
    for (int j = 0; j < 2; ++j)
#pragma unroll
      for (int r = 0; r < 4; ++r) {
        int col = (wave * 2 + j) * 16 + lr;
        int rowl = mt * 16 + lg * 4 + r;
        size_t gr = (size_t)blockIdx.x * 32 + rowl;
        int b = (int)(gr >= SQ);
        int pos = (int)gr - b * SQ;
        int h = col >> 5, dd = col & 31;
        kbf[(((size_t)b * NH + h) * SQ + pos) * DH + dd] = f2bf(dK[mt][j][r]);
        vT[(((size_t)b * NH + h) * DH + dd) * SQ + pos] = f2bf(dV[mt][j][r]);
      }
}

// Flash attention, split-K, XCD-pinned: bh = blockIdx.x & 7 so each (batch,head)
// stays on one XCD -> K/V L2-resident. 4 waves/block, 16 q-rows/wave.
// Pair loaded as f32x4 (256B-per-row bursts) into regs, redistributed via
// wave-private LDS tile to the MFMA C-fragment layout.
__global__ __launch_bounds__(256) void attn(
    const u16* __restrict__ qbf, const u16* __restrict__ kbf, const u16* __restrict__ vT,
    const float* __restrict__ pair, const int* __restrict__ mask_q,
    const int* __restrict__ mask_k,
    float* __restrict__ part_o, float* __restrict__ part_m, float* __restrict__ part_l) {
  __shared__ float pairlds[4][16 * 68];
  __shared__ u16 plds[4][16 * 72];
  const int tid = threadIdx.x, lane = tid & 63, wave = tid >> 6, lr = lane & 15, lg = lane >> 4;
  const int bid = blockIdx.x;
  const int bh = bid & 7;              // low bits -> XCD pinning
  const int rest = bid >> 3;           // 0..191
  const int z = rest / 48, qt = rest - z * 48;
  const int b = bh >> 2;
  const int q0 = qt * 64 + wave * 16;
  const int k0 = z * KCHUNK, kend = k0 + KCHUNK;
  const bf16x8 aq = ld8(qbf + ((size_t)bh * SQ + q0 + lr) * DH + lg * 8);
  float mqm1[4];
#pragma unroll
  for (int r = 0; r < 4; ++r)
    mqm1[r] = 1e9f * ((float)mask_q[b * SQ + q0 + lg * 4 + r] - 1.f);
  float m[4], l[4];
#pragma unroll
  for (int r = 0; r < 4; ++r) { m[r] = -1e30f; l[r] = 0.f; }
  const f32x4 zero = {0.f, 0.f, 0.f, 0.f};
  f32x4 o[2]; o[0] = zero; o[1] = zero;
  // load j: lane (lr,lg) reads f32x4 of row (lg*4+j) at col kb+lr*4.
  const float* pbase = pair + ((size_t)bh * SQ + q0) * SQ;
  float* pwf = pairlds[wave];
  u16* pw = plds[wave];
  f32x4 pf[4];
#pragma unroll
  for (int j = 0; j < 4; ++j)
    pf[j] = __builtin_nontemporal_load(
        reinterpret_cast<const f32x4*>(pbase + (size_t)(lg * 4 + j) * SQ + k0 + lr * 4));
  for (int kb = k0; kb < kend; kb += 64) {
    // write prefetched pair tile (16 rows x 64 cols f32) to wave-private LDS
#pragma unroll
    for (int j = 0; j < 4; ++j)
      *reinterpret_cast<f32x4*>(&pwf[(lg * 4 + j) * 68 + lr * 4]) = pf[j];
    const bool more = (kb + 64) < kend;  // wave-uniform
    if (more) {
#pragma unroll
      for (int j = 0; j < 4; ++j)
        pf[j] = __builtin_nontemporal_load(
            reinterpret_cast<const f32x4*>(pbase + (size_t)(lg * 4 + j) * SQ + kb + 64 + lr * 4));
    }
    f32x4 s[4];
#pragma unroll
    for (int kt = 0; kt < 4; ++kt)
      s[kt] = mfma16(aq, ld8(kbf + ((size_t)bh * SQ + kb + kt * 16 + lr) * DH + lg * 8), zero);
    float mk1[4];
#pragma unroll
    for (int kt = 0; kt < 4; ++kt)
      mk1[kt] = (float)mask_k[b * SQ + kb + kt * 16 + lr] - 1.f;
#pragma unroll
    for (int kt = 0; kt < 4; ++kt)
#pragma unroll
      for (int r = 0; r < 4; ++r) {
        float pv = pwf[(lg * 4 + r) * 68 + kt * 16 + lr];  // 2-way banks: free
        s[kt][r] += fmaf(mqm1[r], mk1[kt], pv);            // exact-1e9 masking preserved
      }
    float alpha[4];
#pragma unroll
    for (int r = 0; r < 4; ++r) {
      float mx = fmaxf(fmaxf(s[0][r], s[1][r]), fmaxf(s[2][r], s[3][r]));
      mx = fmaxf(mx, __shfl_xor(mx, 1));
      mx = fmaxf(mx, __shfl_xor(mx, 2));
      mx = fmaxf(mx, __shfl_xor(mx, 4));
      mx = fmaxf(mx, __shfl_xor(mx, 8));
      float mn = fmaxf(m[r], mx);
      alpha[r] = __expf(m[r] - mn);
      m[r] = mn;
    }
#pragma unroll
    for (int r = 0; r < 4; ++r) {
      float acc = 0.f;
#pragma unroll
      for (int kt = 0; kt < 4; ++kt) {
        float p = __expf(s[kt][r] - m[r]);
        s[kt][r] = p;
        acc += p;
      }
      acc += __shfl_xor(acc, 1); acc += __shfl_xor(acc, 2);
      acc += __shfl_xor(acc, 4); acc += __shfl_xor(acc, 8);
      l[r] = l[r] * alpha[r] + acc;
      o[0][r] *= alpha[r];
      o[1][r] *= alpha[r];
    }
#pragma unroll
    for (int kt = 0; kt < 4; ++kt)
#pragma unroll
      for (int r = 0; r < 4; ++r)
        pw[(lg * 4 + r) * 72 + kt * 16 + lr] = f2bf(s[kt][r]);
#pragma unroll
    for (int kc = 0; kc < 2; ++kc) {
      bf16x8 pa = ld8(pw + lr * 72 + kc * 32 + lg * 8);
#pragma unroll
      for (int hf = 0; hf < 2; ++hf) {
        bf16x8 bv = ld8(vT + ((size_t)bh * DH + hf * 16 + lr) * SQ + kb + kc * 32 + lg * 8);
        o[hf] = mfma16(pa, bv, o[hf]);
      }
    }
  }
  const int zbase = (z * 8 + bh) * SQ;
#pragma unroll
  for (int r = 0; r < 4; ++r) {
    int q = q0 + lg * 4 + r;
    if (lr == 0) {  // m,l uniform across the 16-lane group
      part_m[zbase + q] = m[r];
      part_l[zbase + q] = l[r];
    }
#pragma unroll
    for (int hf = 0; hf < 2; ++hf)
      part_o[((size_t)(zbase + q)) * 32 + hf * 16 + lr] = o[hf][r];
  }
}

// Combine KSPLIT partials, normalize, apply gate, write wa (bf16).
__global__ __launch_bounds__(256) void merge(
    const float* __restrict__ part_o, const float* __restrict__ part_m,
    const float* __restrict__ part_l, const float* __restrict__ gate,
    u16* __restrict__ wa) {
  const int idx = blockIdx.x * 256 + threadIdx.x;  // < 8*SQ*32
  const int c = idx & 31;
  const int row = idx >> 5;  // bh*SQ + q
  float mv[KSPLIT];
  float mm = -1e30f;
#pragma unroll
  for (int z = 0; z < KSPLIT; ++z) {
    mv[z] = part_m[z * 8 * SQ + row];
    mm = fmaxf(mm, mv[z]);
  }
  float l = 0.f, o = 0.f;
#pragma unroll
  for (int z = 0; z < KSPLIT; ++z) {
    float w = __expf(mv[z] - mm);
    l = fmaf(w, part_l[z * 8 * SQ + row], l);
    o = fmaf(w, part_o[((size_t)(z * 8 * SQ + row)) * 32 + c], o);
  }
  const int bh = row / SQ, q = row - bh * SQ;
  const int b = bh >> 2, h = bh & 3;
  const size_t gi = ((size_t)b * SQ + q) * 128 + h * 32 + c;
  wa[gi] = f2bf((o / l) * gate[gi]);
}

// out = (wa @ Wt2) * zc
__global__ __launch_bounds__(256) void finalk(
    const u16* __restrict__ wa, const u16* __restrict__ WTt2,
    const float* __restrict__ zc, float* __restrict__ out) {
  __shared__ u16 awa[32 * 136];
  const int tid = threadIdx.x, rl = tid >> 3, sub = tid & 7, c0 = sub * 16;
  const size_t grow = (size_t)blockIdx.x * 32 + rl;
  const u32x4* srcp = reinterpret_cast<const u32x4*>(wa + grow * 128 + c0);
  u32x4* dstp = reinterpret_cast<u32x4*>(&awa[rl * 136 + c0]);
  dstp[0] = srcp[0];
  dstp[1] = srcp[1];
  __syncthreads();
  const int lane = tid & 63, wave = tid >> 6, lr = lane & 15, lg = lane >> 4;
  f32x4 d[2][2];
  gemm32x128(awa, WTt2, lr, lg, wave, d);
#pragma unroll
  for (int mt = 0; mt < 2; ++mt)
#pragma unroll
    for (int j = 0; j < 2; ++j)
#pragma unroll
      for (int r = 0; r < 4; ++r) {
        int col = (wave * 2 + j) * 16 + lr;
        size_t gr = (size_t)blockIdx.x * 32 + mt * 16 + lg * 4 + r;
        out[gr * 128 + col] = d[mt][j][r] * zc[gr * 128 + col];
      }
}

extern "C" void kernel_launch(void* const* d_in, const int* in_sizes, int n_in,
                              void* d_out, int out_size, void* d_ws, size_t ws_size,
                              hipStream_t stream) {
  const float* x_q   = (const float*)d_in[0];
  const float* x_k   = (const float*)d_in[1];
  const int* mask_q  = (const int*)d_in[2];
  const int* mask_k  = (const int*)d_in[3];
  const float* pair  = (const float*)d_in[4];
  const float* scq   = (const float*)d_in[5];
  const float* sck   = (const float*)d_in[6];
  const float* gamma_cq = (const float*)d_in[7];
  const float* Wsq   = (const float*)d_in[8];
  const float* bsq   = (const float*)d_in[9];
  const float* Wbq   = (const float*)d_in[10];
  const float* gamma_ck = (const float*)d_in[11];
  const float* Wsk   = (const float*)d_in[12];
  const float* bsk   = (const float*)d_in[13];
  const float* Wbk   = (const float*)d_in[14];
  const float* Wq    = (const float*)d_in[15];
  const float* bq    = (const float*)d_in[16];
  const float* Wk    = (const float*)d_in[17];
  const float* Wv    = (const float*)d_in[18];
  const float* Wg    = (const float*)d_in[19];
  const float* Wt2   = (const float*)d_in[20];
  const float* Wzc   = (const float*)d_in[21];
  const float* bzc   = (const float*)d_in[22];

  char* wsb = (char*)d_ws;
  u16* WT       = (u16*)(wsb);               // 10 x 32KB transposed bf16 weights
  u16* qbf      = (u16*)(wsb + 327680);      // [B,H,S,DH] bf16
  u16* kbf      = (u16*)(wsb + 1900544);     // [B,H,S,DH] bf16
  u16* vT       = (u16*)(wsb + 3473408);     // [B,H,DH,S] bf16
  float* gate   = (float*)(wsb + 5046272);   // [B,S,C] f32
  float* zc     = (float*)(wsb + 8192000);   // [B,S,C] f32
  u16* wa       = (u16*)(wsb + 11337728);    // [B,S,C] bf16 (ends 12910592)
  float* part_o = (float*)(wsb + 12910592);  // [KSPLIT,8,SQ,32] f32 (12.6 MB)
  float* part_m = (float*)(wsb + 25493504);  // [KSPLIT,8,SQ] f32
  float* part_l = (float*)(wsb + 25886720);  // [KSPLIT,8,SQ] f32
  float* out    = (float*)d_out;

  PrepSrc ps;
  ps.p[0] = Wsq; ps.p[1] = Wbq; ps.p[2] = Wq; ps.p[3] = Wg; ps.p[4] = Wzc;
  ps.p[5] = Wsk; ps.p[6] = Wbk; ps.p[7] = Wk; ps.p[8] = Wv; ps.p[9] = Wt2;

  hipLaunchKernelGGL(prep, dim3(640), dim3(256), 0, stream, ps, WT);
  hipLaunchKernelGGL(rowblock_q, dim3(192), dim3(256), 0, stream,
                     x_q, scq, gamma_cq, bsq, bq, bzc, WT, qbf, gate, zc);
  hipLaunchKernelGGL(rowblock_k, dim3(192), dim3(256), 0, stream,
                     x_k, sck, gamma_ck, bsk, WT, kbf, vT);
  // grid flattened: bh in low 3 bits -> all blocks of a (batch,head) on one XCD
  hipLaunchKernelGGL(attn, dim3(8 * 48 * KSPLIT), dim3(256), 0, stream,
                     qbf, kbf, vT, pair, mask_q, mask_k, part_o, part_m, part_l);
  hipLaunchKernelGGL(merge, dim3(8 * SQ * 32 / 256), dim3(256), 0, stream,
                     part_o, part_m, part_l, gate, wa);
  hipLaunchKernelGGL(finalk, dim3(192), dim3(256), 0, stream, wa, WT + 9 * 16384, zc, out);
}

// Round 5
// 129.376 us; speedup vs baseline: 1.2021x; 1.0079x over previous
//
#include <hip/hip_runtime.h>
#include <hip/hip_bf16.h>

typedef unsigned short u16;
typedef unsigned int u32;
typedef __attribute__((ext_vector_type(4))) float f32x4;
typedef __attribute__((ext_vector_type(4))) u32 u32x4;
typedef __attribute__((ext_vector_type(8))) __bf16 bf16x8;

#define SQ 3072
#define NH 4
#define DH 32

static __device__ __forceinline__ u16 f2bf(float f) {
  return __builtin_bit_cast(u16, (__bf16)f);
}
static __device__ __forceinline__ u32 pk2(float a, float b) {
  return (u32)f2bf(a) | ((u32)f2bf(b) << 16);
}
static __device__ __forceinline__ bf16x8 ld8(const u16* p) {
  return __builtin_bit_cast(bf16x8, *reinterpret_cast<const u32x4*>(p));
}
static __device__ __forceinline__ f32x4 mfma16(bf16x8 a, bf16x8 b, f32x4 c) {
  return __builtin_amdgcn_mfma_f32_16x16x32_bf16(a, b, c, 0, 0, 0);
}
static __device__ __forceinline__ float sigm(float x) { return 1.0f / (1.0f + __expf(-x)); }
static __device__ __forceinline__ float red8(float v) {
  v += __shfl_xor(v, 1); v += __shfl_xor(v, 2); v += __shfl_xor(v, 4);
  return v;
}

// A: 32x128 bf16 in LDS (row stride 136). B: WT[cout][k] bf16 (128x128, row stride 128).
static __device__ __forceinline__ void gemm32x128(
    const u16* a, const u16* wt, int lr, int lg, int wave, f32x4 d[2][2]) {
  f32x4 z = {0.f, 0.f, 0.f, 0.f};
  d[0][0] = z; d[0][1] = z; d[1][0] = z; d[1][1] = z;
#pragma unroll
  for (int kc = 0; kc < 4; ++kc) {
    int ko = kc * 32 + lg * 8;
    bf16x8 a0 = ld8(a + lr * 136 + ko);
    bf16x8 a1 = ld8(a + (16 + lr) * 136 + ko);
    bf16x8 b0 = ld8(wt + ((wave * 2 + 0) * 16 + lr) * 128 + ko);
    bf16x8 b1 = ld8(wt + ((wave * 2 + 1) * 16 + lr) * 128 + ko);
    d[0][0] = mfma16(a0, b0, d[0][0]);
    d[1][0] = mfma16(a1, b0, d[1][0]);
    d[0][1] = mfma16(a0, b1, d[0][1]);
    d[1][1] = mfma16(a1, b1, d[1][1]);
  }
}

struct PrepSrc { const float* p[10]; };

__global__ __launch_bounds__(256) void prep(PrepSrc s, u16* __restrict__ dst) {
  int bid = blockIdx.x;
  int mm = bid >> 6;
  int idx = ((bid & 63) << 8) + threadIdx.x;  // = cout*128 + k
  int co = idx >> 7, k = idx & 127;
  dst[mm * 16384 + idx] = f2bf(s.p[mm][k * 128 + co]);
}

__global__ __launch_bounds__(256) void rowblock_q(
    const float* __restrict__ x, const float* __restrict__ cond,
    const float* __restrict__ gamma, const float* __restrict__ bs,
    const float* __restrict__ bq, const float* __restrict__ bzc,
    const u16* __restrict__ WT,
    u16* __restrict__ qbf, float* __restrict__ gate, float* __restrict__ zc) {
  __shared__ float xnf[32 * 132];
  __shared__ u16 a_cn[32 * 136];
  __shared__ u16 a_raw[32 * 136];
  __shared__ u16 a_xa[32 * 136];
  const int tid = threadIdx.x;
  const int rl = tid >> 3, sub = tid & 7, c0 = sub * 16;
  const size_t grow = (size_t)blockIdx.x * 32 + rl;

  {
    float xs[16];
    const float4* xr = reinterpret_cast<const float4*>(x + grow * 128 + c0);
#pragma unroll
    for (int i = 0; i < 4; ++i) { float4 t = xr[i]; xs[4*i]=t.x; xs[4*i+1]=t.y; xs[4*i+2]=t.z; xs[4*i+3]=t.w; }
    float s = 0.f;
#pragma unroll
    for (int i = 0; i < 16; ++i) s += xs[i];
    float mean = red8(s) * (1.f / 128.f);
    float vs = 0.f;
#pragma unroll
    for (int i = 0; i < 16; ++i) { float dd = xs[i] - mean; vs += dd * dd; }
    float rstd = rsqrtf(red8(vs) * (1.f / 128.f) + 1e-5f);
    float4* xw = reinterpret_cast<float4*>(&xnf[rl * 132 + c0]);
#pragma unroll
    for (int i = 0; i < 4; ++i) {
      float4 t;
      t.x = (xs[4*i+0] - mean) * rstd; t.y = (xs[4*i+1] - mean) * rstd;
      t.z = (xs[4*i+2] - mean) * rstd; t.w = (xs[4*i+3] - mean) * rstd;
      xw[i] = t;
    }
  }
  {
    float cs[16], gs[16];
    const float4* cr = reinterpret_cast<const float4*>(cond + grow * 128 + c0);
    const float4* gr = reinterpret_cast<const float4*>(gamma + c0);
#pragma unroll
    for (int i = 0; i < 4; ++i) { float4 t = cr[i]; cs[4*i]=t.x; cs[4*i+1]=t.y; cs[4*i+2]=t.z; cs[4*i+3]=t.w; }
#pragma unroll
    for (int i = 0; i < 4; ++i) { float4 t = gr[i]; gs[4*i]=t.x; gs[4*i+1]=t.y; gs[4*i+2]=t.z; gs[4*i+3]=t.w; }
    float s = 0.f;
#pragma unroll
    for (int i = 0; i < 16; ++i) s += cs[i];
    float mean = red8(s) * (1.f / 128.f);
    float vs = 0.f;
#pragma unroll
    for (int i = 0; i < 16; ++i) { float dd = cs[i] - mean; vs += dd * dd; }
    float rstd = rsqrtf(red8(vs) * (1.f / 128.f) + 1e-5f);
    float cn[16];
#pragma unroll
    for (int i = 0; i < 16; ++i) cn[i] = (cs[i] - mean) * rstd * gs[i];
    u32x4* cw = reinterpret_cast<u32x4*>(&a_cn[rl * 136 + c0]);
    u32x4 w0 = {pk2(cn[0],cn[1]), pk2(cn[2],cn[3]), pk2(cn[4],cn[5]), pk2(cn[6],cn[7])};
    u32x4 w1 = {pk2(cn[8],cn[9]), pk2(cn[10],cn[11]), pk2(cn[12],cn[13]), pk2(cn[14],cn[15])};
    cw[0] = w0; cw[1] = w1;
    u32x4* rw = reinterpret_cast<u32x4*>(&a_raw[rl * 136 + c0]);
    u32x4 r0 = {pk2(cs[0],cs[1]), pk2(cs[2],cs[3]), pk2(cs[4],cs[5]), pk2(cs[6],cs[7])};
    u32x4 r1 = {pk2(cs[8],cs[9]), pk2(cs[10],cs[11]), pk2(cs[12],cs[13]), pk2(cs[14],cs[15])};
    rw[0] = r0; rw[1] = r1;
  }
  __syncthreads();
  const int lane = tid & 63, wave = tid >> 6, lr = lane & 15, lg = lane >> 4;
  f32x4 dS[2][2], dB[2][2];
  gemm32x128(a_cn, WT + 0 * 16384, lr, lg, wave, dS);
  gemm32x128(a_cn, WT + 1 * 16384, lr, lg, wave, dB);
#pragma unroll
  for (int mt = 0; mt < 2; ++mt)
#pragma unroll
    for (int j = 0; j < 2; ++j)
#pragma unroll
      for (int r = 0; r < 4; ++r) {
        int col = (wave * 2 + j) * 16 + lr;
        int rowl = mt * 16 + lg * 4 + r;
        float sc = dS[mt][j][r] + bs[col];
        float xa = sigm(sc) * xnf[rowl * 132 + col] + dB[mt][j][r];
        a_xa[rowl * 136 + col] = f2bf(xa);
      }
  __syncthreads();
  f32x4 dQ[2][2], dG[2][2], dZ[2][2];
  gemm32x128(a_xa, WT + 2 * 16384, lr, lg, wave, dQ);
  gemm32x128(a_xa, WT + 3 * 16384, lr, lg, wave, dG);
  gemm32x128(a_raw, WT + 4 * 16384, lr, lg, wave, dZ);
#pragma unroll
  for (int mt = 0; mt < 2; ++mt)
#pragma unroll
    for (int j = 0; j < 2; ++j)
#pragma unroll
      for (int r = 0; r < 4; ++r) {
        int col = (wave * 2 + j) * 16 + lr;
        int rowl = mt * 16 + lg * 4 + r;
        size_t gr = (size_t)blockIdx.x * 32 + rowl;
        int b = (int)(gr >= SQ);
        int pos = (int)gr - b * SQ;
        float qv = (dQ[mt][j][r] + bq[col]) * 0.17677669529663687f;  // Dh^-0.5
        qbf[(((size_t)b * NH + (col >> 5)) * SQ + pos) * DH + (col & 31)] = f2bf(qv);
        gate[gr * 128 + col] = sigm(dG[mt][j][r]);
        zc[gr * 128 + col] = sigm(dZ[mt][j][r] + bzc[col]);
      }
}

__global__ __launch_bounds__(256) void rowblock_k(
    const float* __restrict__ x, const float* __restrict__ cond,
    const float* __restrict__ gamma, const float* __restrict__ bs,
    const u16* __restrict__ WT,
    u16* __restrict__ kbf, u16* __restrict__ vT) {
  __shared__ float xnf[32 * 132];
  __shared__ u16 a_cn[32 * 136];
  __shared__ u16 a_xa[32 * 136];
  const int tid = threadIdx.x;
  const int rl = tid >> 3, sub = tid & 7, c0 = sub * 16;
  const size_t grow = (size_t)blockIdx.x * 32 + rl;
  {
    float xs[16];
    const float4* xr = reinterpret_cast<const float4*>(x + grow * 128 + c0);
#pragma unroll
    for (int i = 0; i < 4; ++i) { float4 t = xr[i]; xs[4*i]=t.x; xs[4*i+1]=t.y; xs[4*i+2]=t.z; xs[4*i+3]=t.w; }
    float s = 0.f;
#pragma unroll
    for (int i = 0; i < 16; ++i) s += xs[i];
    float mean = red8(s) * (1.f / 128.f);
    float vs = 0.f;
#pragma unroll
    for (int i = 0; i < 16; ++i) { float dd = xs[i] - mean; vs += dd * dd; }
    float rstd = rsqrtf(red8(vs) * (1.f / 128.f) + 1e-5f);
    float4* xw = reinterpret_cast<float4*>(&xnf[rl * 132 + c0]);
#pragma unroll
    for (int i = 0; i < 4; ++i) {
      float4 t;
      t.x = (xs[4*i+0] - mean) * rstd; t.y = (xs[4*i+1] - mean) * rstd;
      t.z = (xs[4*i+2] - mean) * rstd; t.w = (xs[4*i+3] - mean) * rstd;
      xw[i] = t;
    }
  }
  {
    float cs[16], gs[16];
    const float4* cr = reinterpret_cast<const float4*>(cond + grow * 128 + c0);
    const float4* gr = reinterpret_cast<const float4*>(gamma + c0);
#pragma unroll
    for (int i = 0; i < 4; ++i) { float4 t = cr[i]; cs[4*i]=t.x; cs[4*i+1]=t.y; cs[4*i+2]=t.z; cs[4*i+3]=t.w; }
#pragma unroll
    for (int i = 0; i < 4; ++i) { float4 t = gr[i]; gs[4*i]=t.x; gs[4*i+1]=t.y; gs[4*i+2]=t.z; gs[4*i+3]=t.w; }
    float s = 0.f;
#pragma unroll
    for (int i = 0; i < 16; ++i) s += cs[i];
    float mean = red8(s) * (1.f / 128.f);
    float vs = 0.f;
#pragma unroll
    for (int i = 0; i < 16; ++i) { float dd = cs[i] - mean; vs += dd * dd; }
    float rstd = rsqrtf(red8(vs) * (1.f / 128.f) + 1e-5f);
    float cn[16];
#pragma unroll
    for (int i = 0; i < 16; ++i) cn[i] = (cs[i] - mean) * rstd * gs[i];
    u32x4* cw = reinterpret_cast<u32x4*>(&a_cn[rl * 136 + c0]);
    u32x4 w0 = {pk2(cn[0],cn[1]), pk2(cn[2],cn[3]), pk2(cn[4],cn[5]), pk2(cn[6],cn[7])};
    u32x4 w1 = {pk2(cn[8],cn[9]), pk2(cn[10],cn[11]), pk2(cn[12],cn[13]), pk2(cn[14],cn[15])};
    cw[0] = w0; cw[1] = w1;
  }
  __syncthreads();
  const int lane = tid & 63, wave = tid >> 6, lr = lane & 15, lg = lane >> 4;
  f32x4 dS[2][2], dB[2][2];
  gemm32x128(a_cn, WT + 5 * 16384, lr, lg, wave, dS);
  gemm32x128(a_cn, WT + 6 * 16384, lr, lg, wave, dB);
#pragma unroll
  for (int mt = 0; mt < 2; ++mt)
#pragma unroll
    for (int j = 0; j < 2; ++j)
#pragma unroll
      for (int r = 0; r < 4; ++r) {
        int col = (wave * 2 + j) * 16 + lr;
        int rowl = mt * 16 + lg * 4 + r;
        float sc = dS[mt][j][r] + bs[col];
        float xa = sigm(sc) * xnf[rowl * 132 + col] + dB[mt][j][r];
        a_xa[rowl * 136 + col] = f2bf(xa);
      }
  __syncthreads();
  f32x4 dK[2][2], dV[2][2];
  gemm32x128(a_xa, WT + 7 * 16384, lr, lg, wave, dK);
  gemm32x128(a_xa, WT + 8 * 16384, lr, lg, wave, dV);
#pragma unroll
  for (int mt = 0; mt < 2; ++mt)
#pragma unroll
    for (int j = 0; j < 2; ++j)
#pragma unroll
      for (int r = 0; r < 4; ++r) {
        int col = (wave * 2 + j) * 16 + lr;
        int rowl = mt * 16 + lg * 4 + r;
        size_t gr = (size_t)blockIdx.x * 32 + rowl;
        int b = (int)(gr >= SQ);
        int pos = (int)gr - b * SQ;
        int h = col >> 5, dd = col & 31;
        kbf[(((size_t)b * NH + h) * SQ + pos) * DH + dd] = f2bf(dK[mt][j][r]);
        vT[(((size_t)b * NH + h) * DH + dd) * SQ + pos] = f2bf(dV[mt][j][r]);
      }
}

// Flash attention, block-cooperative pair staging.
// Block = 16 q-rows x all 3072 keys. 4 waves; tile = 256 keys.
// Staging: wave w loads pair rows w*4..w*4+3 as 64-lane f32x4 = 1KB contiguous
// per instruction (nt), ds_write_b128 into double-buffered LDS tile.
// Compute: wave w owns keys [w*64, w*64+64) of each tile; online softmax per
// wave; 4-way block merge in LDS at the end; gate folded; writes wa.
__global__ __launch_bounds__(256) void attn(
    const u16* __restrict__ qbf, const u16* __restrict__ kbf, const u16* __restrict__ vT,
    const float* __restrict__ pair, const int* __restrict__ mask_q,
    const int* __restrict__ mask_k, const float* __restrict__ gate,
    u16* __restrict__ wa) {
  __shared__ float pbuf[2][16][260];   // pair tile dbuf (stride 260: 2-way banks)
  __shared__ u16 plds[4][16 * 72];     // per-wave P tile
  __shared__ float mb[4][16][34];      // merge: o[0..31], m[32], l[33]
  const int tid = threadIdx.x, lane = tid & 63, w = tid >> 6, lr = lane & 15, lg = lane >> 4;
  const int bid = blockIdx.x;
  const int bh = bid & 7, qt = bid >> 3;  // bh in low bits -> XCD pinning
  const int b = bh >> 2, h = bh & 3;
  const int q0 = qt * 16;
  const bf16x8 aq = ld8(qbf + ((size_t)bh * SQ + q0 + lr) * DH + lg * 8);
  float mqm1[4];
#pragma unroll
  for (int r = 0; r < 4; ++r)
    mqm1[r] = 1e9f * ((float)mask_q[b * SQ + q0 + lg * 4 + r] - 1.f);
  float m[4], l[4];
#pragma unroll
  for (int r = 0; r < 4; ++r) { m[r] = -1e30f; l[r] = 0.f; }
  const f32x4 zero = {0.f, 0.f, 0.f, 0.f};
  f32x4 o[2]; o[0] = zero; o[1] = zero;
  // wave w stages pair rows q0 + w*4 .. +3
  const float* prow0 = pair + ((size_t)bh * SQ + q0 + w * 4) * SQ;
  u16* pw = plds[w];
  f32x4 pf[4];
#pragma unroll
  for (int j = 0; j < 4; ++j)
    pf[j] = __builtin_nontemporal_load(
        reinterpret_cast<const f32x4*>(prow0 + (size_t)j * SQ + lane * 4));
  for (int t = 0; t < 12; ++t) {
    const int bsel = t & 1;
    // write staged tile t (1KB/row, full wave per row)
#pragma unroll
    for (int j = 0; j < 4; ++j)
      *reinterpret_cast<f32x4*>(&pbuf[bsel][w * 4 + j][lane * 4]) = pf[j];
    __syncthreads();  // tile t visible to all waves (drains vmcnt too)
    // issue prefetch of tile t+1 AFTER the barrier so its latency hides
    // under this tile's compute instead of stalling at the barrier drain
    if (t < 11) {
#pragma unroll
      for (int j = 0; j < 4; ++j)
        pf[j] = __builtin_nontemporal_load(
            reinterpret_cast<const f32x4*>(prow0 + (size_t)j * SQ + (t + 1) * 256 + lane * 4));
    }
    const int kb = t * 256 + w * 64;  // this wave's 64-key chunk
    f32x4 s[4];
#pragma unroll
    for (int kt = 0; kt < 4; ++kt)
      s[kt] = mfma16(aq, ld8(kbf + ((size_t)bh * SQ + kb + kt * 16 + lr) * DH + lg * 8), zero);
    float mk1[4];
#pragma unroll
    for (int kt = 0; kt < 4; ++kt)
      mk1[kt] = (float)mask_k[b * SQ + kb + kt * 16 + lr] - 1.f;
#pragma unroll
    for (int kt = 0; kt < 4; ++kt)
#pragma unroll
      for (int r = 0; r < 4; ++r) {
        float pv = pbuf[bsel][lg * 4 + r][w * 64 + kt * 16 + lr];
        s[kt][r] += fmaf(mqm1[r], mk1[kt], pv);  // exact-1e9 masking preserved
      }
    float alpha[4];
#pragma unroll
    for (int r = 0; r < 4; ++r) {
      float mx = fmaxf(fmaxf(s[0][r], s[1][r]), fmaxf(s[2][r], s[3][r]));
      mx = fmaxf(mx, __shfl_xor(mx, 1));
      mx = fmaxf(mx, __shfl_xor(mx, 2));
      mx = fmaxf(mx, __shfl_xor(mx, 4));
      mx = fmaxf(mx, __shfl_xor(mx, 8));
      float mn = fmaxf(m[r], mx);
      alpha[r] = __expf(m[r] - mn);
      m[r] = mn;
    }
#pragma unroll
    for (int r = 0; r < 4; ++r) {
      float acc = 0.f;
#pragma unroll
      for (int kt = 0; kt < 4; ++kt) {
        float p = __expf(s[kt][r] - m[r]);
        s[kt][r] = p;
        acc += p;
      }
      acc += __shfl_xor(acc, 1); acc += __shfl_xor(acc, 2);
      acc += __shfl_xor(acc, 4); acc += __shfl_xor(acc, 8);
      l[r] = l[r] * alpha[r] + acc;
      o[0][r] *= alpha[r];
      o[1][r] *= alpha[r];
    }
#pragma unroll
    for (int kt = 0; kt < 4; ++kt)
#pragma unroll
      for (int r = 0; r < 4; ++r)
        pw[(lg * 4 + r) * 72 + kt * 16 + lr] = f2bf(s[kt][r]);
#pragma unroll
    for (int kc = 0; kc < 2; ++kc) {
      bf16x8 pa = ld8(pw + lr * 72 + kc * 32 + lg * 8);
#pragma unroll
      for (int hf = 0; hf < 2; ++hf) {
        bf16x8 bv = ld8(vT + ((size_t)bh * DH + hf * 16 + lr) * SQ + kb + kc * 32 + lg * 8);
        o[hf] = mfma16(pa, bv, o[hf]);
      }
    }
  }
  // block merge of 4 wave-partials (k-split within block)
#pragma unroll
  for (int r = 0; r < 4; ++r) {
    int row = lg * 4 + r;
    mb[w][row][lr] = o[0][r];
    mb[w][row][16 + lr] = o[1][r];
    if (lr == 0) { mb[w][row][32] = m[r]; mb[w][row][33] = l[r]; }
  }
  __syncthreads();
#pragma unroll
  for (int it = 0; it < 2; ++it) {
    int q = (tid >> 5) + it * 8;  // 0..15
    int d = tid & 31;
    float m0 = mb[0][q][32], m1 = mb[1][q][32], m2 = mb[2][q][32], m3 = mb[3][q][32];
    float mm = fmaxf(fmaxf(m0, m1), fmaxf(m2, m3));
    float ll = 0.f, oo = 0.f;
#pragma unroll
    for (int w4 = 0; w4 < 4; ++w4) {
      float e = __expf(mb[w4][q][32] - mm);
      ll = fmaf(e, mb[w4][q][33], ll);
      oo = fmaf(e, mb[w4][q][d], oo);
    }
    size_t gi = ((size_t)b * SQ + q0 + q) * 128 + h * 32 + d;
    wa[gi] = f2bf((oo / ll) * gate[gi]);
  }
}

// out = (wa @ Wt2) * zc
__global__ __launch_bounds__(256) void finalk(
    const u16* __restrict__ wa, const u16* __restrict__ WTt2,
    const float* __restrict__ zc, float* __restrict__ out) {
  __shared__ u16 awa[32 * 136];
  const int tid = threadIdx.x, rl = tid >> 3, sub = tid & 7, c0 = sub * 16;
  const size_t grow = (size_t)blockIdx.x * 32 + rl;
  const u32x4* srcp = reinterpret_cast<const u32x4*>(wa + grow * 128 + c0);
  u32x4* dstp = reinterpret_cast<u32x4*>(&awa[rl * 136 + c0]);
  dstp[0] = srcp[0];
  dstp[1] = srcp[1];
  __syncthreads();
  const int lane = tid & 63, wave = tid >> 6, lr = lane & 15, lg = lane >> 4;
  f32x4 d[2][2];
  gemm32x128(awa, WTt2, lr, lg, wave, d);
#pragma unroll
  for (int mt = 0; mt < 2; ++mt)
#pragma unroll
    for (int j = 0; j < 2; ++j)
#pragma unroll
      for (int r = 0; r < 4; ++r) {
        int col = (wave * 2 + j) * 16 + lr;
        size_t gr = (size_t)blockIdx.x * 32 + mt * 16 + lg * 4 + r;
        out[gr * 128 + col] = d[mt][j][r] * zc[gr * 128 + col];
      }
}

extern "C" void kernel_launch(void* const* d_in, const int* in_sizes, int n_in,
                              void* d_out, int out_size, void* d_ws, size_t ws_size,
                              hipStream_t stream) {
  const float* x_q   = (const float*)d_in[0];
  const float* x_k   = (const float*)d_in[1];
  const int* mask_q  = (const int*)d_in[2];
  const int* mask_k  = (const int*)d_in[3];
  const float* pair  = (const float*)d_in[4];
  const float* scq   = (const float*)d_in[5];
  const float* sck   = (const float*)d_in[6];
  const float* gamma_cq = (const float*)d_in[7];
  const float* Wsq   = (const float*)d_in[8];
  const float* bsq   = (const float*)d_in[9];
  const float* Wbq   = (const float*)d_in[10];
  const float* gamma_ck = (const float*)d_in[11];
  const float* Wsk   = (const float*)d_in[12];
  const float* bsk   = (const float*)d_in[13];
  const float* Wbk   = (const float*)d_in[14];
  const float* Wq    = (const float*)d_in[15];
  const float* bq    = (const float*)d_in[16];
  const float* Wk    = (const float*)d_in[17];
  const float* Wv    = (const float*)d_in[18];
  const float* Wg    = (const float*)d_in[19];
  const float* Wt2   = (const float*)d_in[20];
  const float* Wzc   = (const float*)d_in[21];
  const float* bzc   = (const float*)d_in[22];

  char* wsb = (char*)d_ws;
  u16* WT     = (u16*)(wsb);                 // 10 x 32KB transposed bf16 weights
  u16* qbf    = (u16*)(wsb + 327680);        // [B,H,S,DH] bf16
  u16* kbf    = (u16*)(wsb + 1900544);       // [B,H,S,DH] bf16
  u16* vT     = (u16*)(wsb + 3473408);       // [B,H,DH,S] bf16
  float* gate = (float*)(wsb + 5046272);     // [B,S,C] f32
  float* zc   = (float*)(wsb + 8192000);     // [B,S,C] f32
  u16* wa     = (u16*)(wsb + 11337728);      // [B,S,C] bf16
  float* out  = (float*)d_out;

  PrepSrc ps;
  ps.p[0] = Wsq; ps.p[1] = Wbq; ps.p[2] = Wq; ps.p[3] = Wg; ps.p[4] = Wzc;
  ps.p[5] = Wsk; ps.p[6] = Wbk; ps.p[7] = Wk; ps.p[8] = Wv; ps.p[9] = Wt2;

  hipLaunchKernelGGL(prep, dim3(640), dim3(256), 0, stream, ps, WT);
  hipLaunchKernelGGL(rowblock_q, dim3(192), dim3(256), 0, stream,
                     x_q, scq, gamma_cq, bsq, bq, bzc, WT, qbf, gate, zc);
  hipLaunchKernelGGL(rowblock_k, dim3(192), dim3(256), 0, stream,
                     x_k, sck, gamma_ck, bsk, WT, kbf, vT);
  // 1536 blocks: bh in low 3 bits (XCD pin), 192 q-tiles of 16 rows
  hipLaunchKernelGGL(attn, dim3(8 * 192), dim3(256), 0, stream,
                     qbf, kbf, vT, pair, mask_q, mask_k, gate, wa);
  hipLaunchKernelGGL(finalk, dim3(192), dim3(256), 0, stream, wa, WT + 9 * 16384, zc, out);
}